// Round 1
// baseline (1651.792 us; speedup 1.0000x reference)
//
#include <hip/hip_runtime.h>
#include <math.h>

#define Bn 32
#define Cn 32
#define Ln 16384
#define NF 511      // number of spectrogram frames
#define NB 33       // rfft bins of 64-pt window
#define MAXSEG 512
#define TB 8192     // total spectral bins per batch (sum of nf over segments = L/2)
#define PEN 5.0

// ---------------- sig = x.mean(axis=channels), float32 sequential (numpy axis-0 reduce order)
__global__ void k_sig(const float* __restrict__ x, float* __restrict__ sig) {
    int idx = blockIdx.x * 256 + threadIdx.x;
    if (idx >= Bn * Ln) return;
    int b = idx >> 14;
    int t = idx & (Ln - 1);
    const float* p = x + ((size_t)b * Cn) * Ln + t;
    float a = p[0];
    #pragma unroll
    for (int c = 1; c < Cn; c++) a += p[(size_t)c * Ln];
    sig[idx] = a / 32.0f;
}

// ---------------- frame means: numpy scalar pairwise 8-accumulator pattern, n=64, float32
__global__ void k_fmean(const float* __restrict__ sig, float* __restrict__ fm) {
    int idx = blockIdx.x * 256 + threadIdx.x;
    if (idx >= Bn * NF) return;
    int b = idx / NF, f = idx - b * NF;
    const float* a = sig + b * Ln + f * 32;
    float r[8];
    #pragma unroll
    for (int j = 0; j < 8; j++) r[j] = a[j];
    #pragma unroll
    for (int base = 8; base < 64; base += 8)
        #pragma unroll
        for (int j = 0; j < 8; j++) r[j] += a[base + j];
    float res = ((r[0] + r[1]) + (r[2] + r[3])) + ((r[4] + r[5]) + (r[6] + r[7]));
    fm[idx] = res / 64.0f;
}

// ---------------- feats = log(|rfft(hann * (frame - mean))|^2 + 1e-8), double
__global__ void k_feats(const float* __restrict__ sig, const float* __restrict__ fm,
                        double* __restrict__ feats) {
    __shared__ double v[64], ct[64], stb[64];
    int bf = blockIdx.x;
    int b = bf / NF, f = bf - b * NF;
    int i = threadIdx.x;  // 0..63
    double ang = (2.0 * M_PI * (double)i) / 64.0;
    double sn, cx;
    sincos(ang, &sn, &cx);
    ct[i] = cx; stb[i] = sn;
    int n2 = 2 * i - 63;                       // np.hanning: arange(1-M, M, 2)
    double w = 0.5 + 0.5 * cos((M_PI * (double)n2) / 63.0);
    float m = fm[bf];
    v[i] = (double)(sig[b * Ln + f * 32 + i] - m) * w;   // f32 subtract, f64 window mult
    __syncthreads();
    if (i < NB) {
        double re = 0.0, im = 0.0;
        for (int t = 0; t < 64; t++) {
            int j = (t * i) & 63;
            re += v[t] * ct[j];
            im += v[t] * stb[j];
        }
        double spec = re * re + im * im;
        feats[(size_t)bf * NB + i] = log(spec + 1e-8);
    }
}

// ---------------- cs / cs2 cumsums (sequential double, numpy cumsum order)
__global__ void k_cumsum(const double* __restrict__ feats, double* __restrict__ cs,
                         double* __restrict__ cs2) {
    int idx = blockIdx.x * 256 + threadIdx.x;
    if (idx >= Bn * NB) return;
    int b = idx / NB, d = idx - b * NB;
    const double* fp = feats + (size_t)b * NF * NB + d;
    double* c1 = cs + (size_t)b * 512 * NB + d;
    double* c2 = cs2 + (size_t)b * 512 * NB + d;
    double a1 = 0.0, a2 = 0.0;
    c1[0] = 0.0; c2[0] = 0.0;
    for (int t = 0; t < NF; t++) {
        double vv = fp[(size_t)t * NB];
        a1 += vv;
        a2 += vv * vv;
        c1[(size_t)(t + 1) * NB] = a1;
        c2[(size_t)(t + 1) * NB] = a2;
    }
}

// ---------------- precompute cost(c,t) for all pairs, massively parallel, exact numpy op order
__global__ __launch_bounds__(256) void k_cost(const double* __restrict__ cs,
                                              const double* __restrict__ cs2,
                                              double* __restrict__ costM) {
    int t = blockIdx.x + 1;   // 1..NF
    int b = blockIdx.y;
    const double* c1 = cs + (size_t)b * 512 * NB;
    const double* c2 = cs2 + (size_t)b * 512 * NB;
    __shared__ double sct1[NB], sct2[NB];
    if (threadIdx.x < NB) {
        sct1[threadIdx.x] = c1[(size_t)t * NB + threadIdx.x];
        sct2[threadIdx.x] = c2[(size_t)t * NB + threadIdx.x];
    }
    __syncthreads();
    double* outp = costM + ((size_t)b * 512 + (size_t)t) * 512;
    for (int c = threadIdx.x; c < t; c += 256) {
        double nn = (double)(t - c);
        const double* p1 = c1 + (size_t)c * NB;
        const double* p2 = c2 + (size_t)c * NB;
        // numpy pairwise sum over 33 dims: 8 accumulators + remainder
        double r[8];
        #pragma unroll
        for (int j = 0; j < 8; j++) {
            double ss = sct1[j] - p1[j]; double s2 = sct2[j] - p2[j];
            r[j] = s2 - ss * ss / nn;
        }
        #pragma unroll
        for (int base = 8; base < 32; base += 8)
            #pragma unroll
            for (int j = 0; j < 8; j++) {
                int d = base + j;
                double ss = sct1[d] - p1[d]; double s2 = sct2[d] - p2[d];
                r[j] += s2 - ss * ss / nn;
            }
        double res = ((r[0] + r[1]) + (r[2] + r[3])) + ((r[4] + r[5]) + (r[6] + r[7]));
        { double ss = sct1[32] - p1[32]; double s2 = sct2[32] - p2[32]; res += s2 - ss * ss / nn; }
        outp[c] = res;
    }
}

// ---------------- PELT DP with precomputed costs: one wave/batch, bitmask candidates,
// Fc in registers. Depth-4 software-pipelined row prefetch: the t-loop is unrolled x4
// with statically-named register row buffers (r0..r3 current, n0..n3 in flight).
// Loads for rows t+4..t+7 are issued before the 4 DP steps of rows t..t+3, so ~4
// iterations of shfl-chain compute hide the L3/HBM row-fetch latency (the previous
// depth-1 prefetch left ~1400 cy/iter of unhidden latency).
__global__ __launch_bounds__(64, 1) void k_pelt(const double* __restrict__ costM,
                                                int* __restrict__ prevG) {
    int b = blockIdx.x;
    int lane = threadIdx.x;
    const double* cm = costM + (size_t)b * 512 * 512;

    unsigned long long cmask[8] = {1ull, 0, 0, 0, 0, 0, 0, 0};
    double fcreg[8];   // Fc[p*64 + lane], owned by this lane
    #pragma unroll
    for (int p = 0; p < 8; p++) fcreg[p] = INFINITY;
    if (lane == 0) fcreg[0] = -PEN;   // Fc[0]

    // one DP step for row t held in cur[8] (all cur indices compile-time after unroll)
    auto step = [&](int t, double (&cur)[8]) {
        double vals[8];
        double bv = INFINITY; int bc = 0x7fffffff;
        #pragma unroll
        for (int p = 0; p < 8; p++) {
            int c = (p << 6) + lane;
            bool isc = ((cmask[p] >> lane) & 1ull) != 0ull;
            double v = isc ? (fcreg[p] + cur[p] + PEN) : INFINITY;
            vals[p] = v;
            if (v < bv) { bv = v; bc = c; }   // ascending-c pass order: strict < = first occurrence
        }
        // lexicographic (val, c) butterfly argmin across 64 lanes
        #pragma unroll
        for (int off = 1; off < 64; off <<= 1) {
            double ov = __shfl_xor(bv, off);
            int oc = __shfl_xor(bc, off);
            if (ov < bv || (ov == bv && oc < bc)) { bv = ov; bc = oc; }
        }
        double thr = bv + PEN;
        if (lane == 0) prevG[b * 512 + t] = bc;
        // latch Fc[t] into the owning lane's register
        #pragma unroll
        for (int p = 0; p < 8; p++)
            if (p == (t >> 6) && lane == (t & 63)) fcreg[p] = bv;
        // prune candidates (bitmask &= keep), then add candidate t (static index form)
        #pragma unroll
        for (int p = 0; p < 8; p++) {
            unsigned long long keep = __ballot(vals[p] <= thr);
            cmask[p] &= keep;
        }
        int tp = t >> 6;
        unsigned long long tbit = 1ull << (t & 63);
        #pragma unroll
        for (int p = 0; p < 8; p++)
            if (p == tp) cmask[p] |= tbit;
    };

    // preload rows 1..4
    double r0[8], r1[8], r2[8], r3[8];
    #pragma unroll
    for (int p = 0; p < 8; p++) {
        r0[p] = cm[(size_t)1 * 512 + (p << 6) + lane];
        r1[p] = cm[(size_t)2 * 512 + (p << 6) + lane];
        r2[p] = cm[(size_t)3 * 512 + (p << 6) + lane];
        r3[p] = cm[(size_t)4 * 512 + (p << 6) + lane];
    }

    int t = 1;
    for (; t + 3 <= NF - 3; t += 4) {          // groups t..t+3 for t = 1,5,...,505 (covers 1..508)
        double n0[8], n1[8], n2[8], n3[8];
        int q0 = t + 4, q1 = t + 5, q2 = t + 6, q3 = t + 7;
        if (q3 > NF) q3 = NF;                  // only q3 can exceed NF (clamped dup, unused in tail)
        #pragma unroll
        for (int p = 0; p < 8; p++) {
            n0[p] = cm[(size_t)q0 * 512 + (p << 6) + lane];
            n1[p] = cm[(size_t)q1 * 512 + (p << 6) + lane];
            n2[p] = cm[(size_t)q2 * 512 + (p << 6) + lane];
            n3[p] = cm[(size_t)q3 * 512 + (p << 6) + lane];
        }
        step(t, r0); step(t + 1, r1); step(t + 2, r2); step(t + 3, r3);
        #pragma unroll
        for (int p = 0; p < 8; p++) { r0[p] = n0[p]; r1[p] = n1[p]; r2[p] = n2[p]; r3[p] = n3[p]; }
    }
    // tail: t = 509, 510, 511 (rows already resident in r0..r2)
    if (t     <= NF) step(t,     r0);
    if (t + 1 <= NF) step(t + 1, r1);
    if (t + 2 <= NF) step(t + 2, r2);
    if (t + 3 <= NF) step(t + 3, r3);
}

// ---------------- fallback PELT (round-2 version) if workspace can't hold cost matrix
__global__ __launch_bounds__(64) void k_pelt_slow(const double* __restrict__ cs,
                                                  const double* __restrict__ cs2,
                                                  int* __restrict__ prevG) {
    __shared__ double sFc[512];
    __shared__ double sVal[512];
    __shared__ unsigned short sCand[512];
    int b = blockIdx.x;
    int lane = threadIdx.x;
    const double* c1 = cs + (size_t)b * 512 * NB;
    const double* c2 = cs2 + (size_t)b * 512 * NB;
    if (lane == 0) { sFc[0] = -PEN; sCand[0] = 0; }
    __syncthreads();
    int ncand = 1;
    for (int t = 1; t <= NF; t++) {
        const double* ct1 = c1 + (size_t)t * NB;
        const double* ct2 = c2 + (size_t)t * NB;
        int passes = (ncand + 63) >> 6;
        double bmv = INFINITY;
        int bmi = 0x7fffffff;
        for (int p = 0; p < passes; p++) {
            int slot = (p << 6) + lane;
            double val = INFINITY;
            if (slot < ncand) {
                int cc = sCand[slot];
                double nn = (double)(t - cc);
                const double* p1 = c1 + (size_t)cc * NB;
                const double* p2 = c2 + (size_t)cc * NB;
                double r[8];
                #pragma unroll
                for (int j = 0; j < 8; j++) {
                    double ss = ct1[j] - p1[j]; double s2 = ct2[j] - p2[j];
                    r[j] = s2 - ss * ss / nn;
                }
                #pragma unroll
                for (int base = 8; base < 32; base += 8)
                    #pragma unroll
                    for (int j = 0; j < 8; j++) {
                        int d = base + j;
                        double ss = ct1[d] - p1[d]; double s2 = ct2[d] - p2[d];
                        r[j] += s2 - ss * ss / nn;
                    }
                double res = ((r[0] + r[1]) + (r[2] + r[3])) + ((r[4] + r[5]) + (r[6] + r[7]));
                { double ss = ct1[32] - p1[32]; double s2 = ct2[32] - p2[32]; res += s2 - ss * ss / nn; }
                val = sFc[cc] + res + PEN;
                if (val < bmv) { bmv = val; bmi = slot; }
            }
            sVal[slot] = val;
        }
        #pragma unroll
        for (int off = 1; off < 64; off <<= 1) {
            double ov = __shfl_xor(bmv, off);
            int oi = __shfl_xor(bmi, off);
            if (ov < bmv || (ov == bmv && oi < bmi)) { bmv = ov; bmi = oi; }
        }
        double thr = bmv + PEN;
        if (lane == 0) {
            sFc[t] = bmv;
            prevG[b * 512 + t] = (int)sCand[bmi];
        }
        __syncthreads();
        int base = 0;
        for (int p = 0; p < passes; p++) {
            int slot = (p << 6) + lane;
            int cc = (slot < ncand) ? (int)sCand[slot] : 0;
            bool keep = (slot < ncand) && (sVal[slot] <= thr);
            unsigned long long mask = __ballot(keep);
            if (keep) sCand[base + __popcll(mask & ((1ull << lane) - 1ull))] = (unsigned short)cc;
            base += (int)__popcll(mask);
        }
        if (lane == 0) sCand[base] = (unsigned short)t;
        ncand = base + 1;
        __syncthreads();
    }
}

// ---------------- backtrack + bounds + segment table + bin offsets (1 thread per batch)
__global__ void k_bounds(const int* __restrict__ prevG, int* __restrict__ bps, int* __restrict__ bnds,
                         int* __restrict__ segS, int* __restrict__ segE, int* __restrict__ nsegA,
                         int* __restrict__ binoff) {
    int b = threadIdx.x;
    if (b >= Bn) return;
    const int* pv = prevG + b * 512;
    int* bp = bps + b * 512;
    int* bd = bnds + b * 520;
    int cnt = 0, t = NF;
    while (t > 0) { bp[cnt++] = t; t = pv[t]; }
    int nb = 1; bd[0] = 0;
    for (int i = cnt - 1; i >= 1; --i) {
        int k = bp[i];
        int bb = 32 * k;
        if (bb > Ln) bb = Ln;
        if (bb - bd[nb - 1] >= 8) bd[nb++] = bb;
    }
    if (Ln - bd[nb - 1] < 8 && nb > 1) nb--;
    bd[nb++] = Ln;
    int ns = nb - 1;
    nsegA[b] = ns;
    int off = 0;
    for (int j = 0; j < ns; j++) {
        int s = bd[j], e = bd[j + 1];
        segS[b * 512 + j] = s; segE[b * 512 + j] = e;
        binoff[b * 513 + j] = off;
        off += (e - s) >> 1;
    }
    binoff[b * 513 + ns] = off;
}

// ---------------- per-segment mean (double)
__global__ void k_segmean(const float* __restrict__ sig, const int* __restrict__ segS,
                          const int* __restrict__ segE, const int* __restrict__ nsegA,
                          double* __restrict__ segMean) {
    __shared__ double red[256];
    int b = blockIdx.y, j = blockIdx.x;
    if (j >= nsegA[b]) return;
    int s = segS[b * 512 + j], e = segE[b * 512 + j];
    double acc = 0.0;
    for (int i = s + threadIdx.x; i < e; i += 256) acc += (double)sig[b * Ln + i];
    red[threadIdx.x] = acc;
    __syncthreads();
    for (int st = 128; st >= 1; st >>= 1) {
        if (threadIdx.x < st) red[threadIdx.x] += red[threadIdx.x + st];
        __syncthreads();
    }
    if (threadIdx.x == 0) segMean[b * 512 + j] = red[0] / (double)(e - s);
}

// ---------------- segment DFT: one wave per (batch, bin-slot), rotation recurrence in double
__global__ __launch_bounds__(256) void k_spec(const float* __restrict__ sig,
                                              const double* __restrict__ segMean,
                                              const int* __restrict__ segS, const int* __restrict__ segE,
                                              const int* __restrict__ nsegA, const int* __restrict__ binoff,
                                              double* __restrict__ spec) {
    int b = blockIdx.y;
    int wv = threadIdx.x >> 6, lane = threadIdx.x & 63;
    int slot = blockIdx.x * 4 + wv;
    int ns = nsegA[b];
    const int* off = binoff + b * 513;
    if (slot >= off[ns]) return;
    int lo = 0, hi = ns - 1;
    while (lo < hi) { int mid = (lo + hi + 1) >> 1; if (off[mid] <= slot) lo = mid; else hi = mid - 1; }
    int j = lo;
    int s = segS[b * 512 + j], e = segE[b * 512 + j], n = e - s;
    int k = slot - off[j] + 1;
    float m32 = (float)segMean[b * 512 + j];
    long j0 = ((long)lane * (long)k) % (long)n;
    long js = (64L * (long)k) % (long)n;
    double a0 = (2.0 * M_PI * (double)j0) / (double)n;
    double as = (2.0 * M_PI * (double)js) / (double)n;
    double cr, sr, cb, sb;
    sincos(a0, &sr, &cr);
    sincos(as, &sb, &cb);
    double re = 0.0, im = 0.0;
    const float* sp = sig + b * Ln + s;
    for (int tt = lane; tt < n; tt += 64) {
        double v = (double)(sp[tt] - m32);
        re += v * cr;
        im += v * sr;
        double nc = cr * cb - sr * sb;
        sr = sr * cb + cr * sb;
        cr = nc;
    }
    #pragma unroll
    for (int o = 32; o >= 1; o >>= 1) { re += __shfl_down(re, o); im += __shfl_down(im, o); }
    if (lane == 0) spec[(size_t)b * TB + slot] = re * re + im * im;
}

// ---------------- per-segment stats
__global__ void k_stats(const double* __restrict__ spec, const int* __restrict__ segS,
                        const int* __restrict__ segE, const int* __restrict__ nsegA,
                        const int* __restrict__ binoff, int* __restrict__ segPL,
                        double* __restrict__ segDP, double* __restrict__ segBW,
                        int* __restrict__ segNT) {
    __shared__ double rv[256]; __shared__ int ri[256];
    __shared__ double rt[256], rs[256];
    __shared__ double sC, sTot;
    int b = blockIdx.y, j = blockIdx.x;
    if (j >= nsegA[b]) return;
    int s = segS[b * 512 + j], e = segE[b * 512 + j], n = e - s, nf = n >> 1;
    const double* base = spec + (size_t)b * TB + binoff[b * 513 + j];
    int tid = threadIdx.x;
    double mv = -INFINITY; int mi = 0x7fffffff; double tot = 0.0, s1 = 0.0;
    for (int i = tid; i < nf; i += 256) {
        double vv = base[i];
        double f = (double)(i + 1) / (double)nf;
        tot += vv; s1 += vv * f;
        if (vv > mv) { mv = vv; mi = i; }
    }
    rv[tid] = mv; ri[tid] = mi; rt[tid] = tot; rs[tid] = s1;
    __syncthreads();
    for (int st = 128; st >= 1; st >>= 1) {
        if (tid < st) {
            double ov = rv[tid + st]; int oi = ri[tid + st];
            if (ov > rv[tid] || (ov == rv[tid] && oi < ri[tid])) { rv[tid] = ov; ri[tid] = oi; }
            rt[tid] += rt[tid + st]; rs[tid] += rs[tid + st];
        }
        __syncthreads();
    }
    if (tid == 0) { sTot = rt[0]; sC = rs[0] / rt[0]; }
    __syncthreads();
    double c = sC, totv = sTot;
    double s2 = 0.0;
    for (int i = tid; i < nf; i += 256) {
        double f = (double)(i + 1) / (double)nf;
        double d = f - c;
        s2 += base[i] * d * d;
    }
    rt[tid] = s2;
    __syncthreads();
    for (int st = 128; st >= 1; st >>= 1) {
        if (tid < st) rt[tid] += rt[tid + st];
        __syncthreads();
    }
    if (tid == 0) {
        double dp, bw;
        if (n < 4) { dp = (double)(n > 0 ? n : 1); bw = 0.0; }
        else if (!(totv > 0.0)) { dp = (double)n; bw = 0.0; }
        else { int kk = ri[0] + 1; dp = (double)n / (double)kk; bw = sqrt(rt[0] / totv); }
        double raw = 1.0 * dp / (1.0 + 1.0 * bw);
        double rr = rint(raw / 2.0);          // Python round(): half-to-even
        long pl = 2L * (long)rr;
        if (pl < 8) pl = 8;
        if (pl > 64) pl = 64;
        int nfull = n / (int)pl;
        int ntok = nfull + ((nfull * (int)pl < n) ? 1 : 0);
        segPL[b * 512 + j] = (int)pl; segDP[b * 512 + j] = dp;
        segBW[b * 512 + j] = bw; segNT[b * 512 + j] = ntok;
    }
}

// ---------------- token prefix offsets per batch
__global__ void k_tokpref(const int* __restrict__ nsegA, const int* __restrict__ segNT,
                          int* __restrict__ tokoff, int* __restrict__ ntokA) {
    int b = threadIdx.x;
    if (b >= Bn) return;
    int ns = nsegA[b]; int off = 0;
    for (int j = 0; j < ns; j++) { tokoff[b * 513 + j] = off; off += segNT[b * 512 + j]; }
    tokoff[b * 513 + ns] = off;
    ntokA[b] = off;
}

// ---------------- fill all outputs: one block per (batch, token)
__global__ __launch_bounds__(256) void k_fill(const float* __restrict__ x,
                                              const int* __restrict__ segS, const int* __restrict__ segE,
                                              const int* __restrict__ segPL, const double* __restrict__ segDP,
                                              const double* __restrict__ segBW, const int* __restrict__ nsegA,
                                              const int* __restrict__ tokoff, const int* __restrict__ ntokA,
                                              float* __restrict__ out, int MT) {
    int b = blockIdx.y, tok = blockIdx.x;
    int nt = ntokA[b];
    if (tok >= nt) return;
    int ns = nsegA[b];
    const int* toff = tokoff + b * 513;
    int lo = 0, hi = ns - 1;
    while (lo < hi) { int mid = (lo + hi + 1) >> 1; if (toff[mid] <= tok) lo = mid; else hi = mid - 1; }
    int j = lo;
    int s = segS[b * 512 + j], e = segE[b * 512 + j], pl = segPL[b * 512 + j];
    int idx = tok - toff[j];
    int nfull = (e - s) / pl;
    int st, en;
    if (idx < nfull) { st = s + idx * pl; en = st + pl; }
    else { st = s + nfull * pl; en = e; }
    int ilen = en - st;
    float scale = (float)ilen / 16.0f;
    int tid = threadIdx.x;
    size_t pbase = ((size_t)(b * MT + tok)) * (Cn * 16);
    const float* xb = x + (size_t)b * Cn * Ln;
    #pragma unroll
    for (int r = 0; r < 2; r++) {
        int eidx = tid + r * 256;
        int c = eidx >> 4, jo = eidx & 15;
        float coords = ((float)jo + 0.5f) * scale - 0.5f;
        if (coords < 0.0f) coords = 0.0f;
        float mx = (float)(ilen - 1);
        if (coords > mx) coords = mx;
        int l2 = (int)floorf(coords);
        int h2 = l2 + 1;
        if (h2 > ilen - 1) h2 = ilen - 1;
        float w = coords - (float)l2;
        const float* xc = xb + (size_t)c * Ln + st;
        out[pbase + eidx] = xc[l2] * (1.0f - w) + xc[h2] * w;
    }
    if (tid == 0) {
        size_t BT = (size_t)Bn * MT;
        size_t o_mask = BT * 512;
        size_t pos = (size_t)b * MT + tok;
        out[o_mask + pos] = 1.0f;                                  // mask
        out[o_mask + BT + pos] = (float)st;                        // start
        out[o_mask + 2 * BT + pos] = (float)en;                    // end
        out[o_mask + 3 * BT + pos] = (((float)st + (float)en) - 1.0f) * 0.5f / 16383.0f;  // center
        out[o_mask + 4 * BT + pos] = (float)(en - st) / 16384.0f;  // span
        double dp = segDP[b * 512 + j], bwv = segBW[b * 512 + j];
        size_t o_rg = o_mask + 5 * BT;
        out[o_rg + pos * 3 + 0] = (float)(dp / 16384.0);
        out[o_rg + pos * 3 + 1] = (float)bwv;
        out[o_rg + pos * 3 + 2] = (float)((double)(e - s) / 16384.0);
        if (tok == 0) out[o_mask + 8 * BT + b] = (float)nt;        // n_tok
    }
}

extern "C" void kernel_launch(void* const* d_in, const int* in_sizes, int n_in,
                              void* d_out, int out_size, void* d_ws, size_t ws_size,
                              hipStream_t stream) {
    (void)in_sizes; (void)n_in;
    const float* x = (const float*)d_in[0];
    float* out = (float*)d_out;
    char* ws = (char*)d_ws;
    size_t o = 0;
    auto alloc = [&](size_t bytes) -> char* {
        char* r = ws + o;
        o = (o + bytes + 511) & ~(size_t)511;
        return r;
    };
    float* sig = (float*)alloc((size_t)Bn * Ln * 4);
    float* fm = (float*)alloc((size_t)Bn * NF * 4);
    double* feats = (double*)alloc((size_t)Bn * NF * NB * 8);
    double* cs = (double*)alloc((size_t)Bn * 512 * NB * 8);
    double* cs2 = (double*)alloc((size_t)Bn * 512 * NB * 8);
    int* prevG = (int*)alloc((size_t)Bn * 512 * 4);
    int* bps = (int*)alloc((size_t)Bn * 512 * 4);
    int* bnds = (int*)alloc((size_t)Bn * 520 * 4);
    int* nsegA = (int*)alloc((size_t)Bn * 4);
    int* segS = (int*)alloc((size_t)Bn * 512 * 4);
    int* segE = (int*)alloc((size_t)Bn * 512 * 4);
    int* segPL = (int*)alloc((size_t)Bn * 512 * 4);
    int* segNT = (int*)alloc((size_t)Bn * 512 * 4);
    double* segDP = (double*)alloc((size_t)Bn * 512 * 8);
    double* segBW = (double*)alloc((size_t)Bn * 512 * 8);
    double* segMean = (double*)alloc((size_t)Bn * 512 * 8);
    int* binoff = (int*)alloc((size_t)Bn * 513 * 4);
    int* tokoff = (int*)alloc((size_t)Bn * 513 * 4);
    int* ntokA = (int*)alloc((size_t)Bn * 4);
    double* spec = (double*)alloc((size_t)Bn * TB * 8);
    size_t costBytes = (size_t)Bn * 512 * 512 * 8;   // 67 MB
    double* costM = (double*)alloc(costBytes);
    bool haveCost = (o <= ws_size);

    int MT = (out_size / Bn - 1) / 520;   // out_size = Bn*(MT*520 + 1)

    hipMemsetAsync(d_out, 0, (size_t)out_size * 4, stream);
    k_sig<<<(Bn * Ln + 255) / 256, 256, 0, stream>>>(x, sig);
    k_fmean<<<(Bn * NF + 255) / 256, 256, 0, stream>>>(sig, fm);
    k_feats<<<Bn * NF, 64, 0, stream>>>(sig, fm, feats);
    k_cumsum<<<(Bn * NB + 255) / 256, 256, 0, stream>>>(feats, cs, cs2);
    if (haveCost) {
        k_cost<<<dim3(NF, Bn), 256, 0, stream>>>(cs, cs2, costM);
        k_pelt<<<Bn, 64, 0, stream>>>(costM, prevG);
    } else {
        k_pelt_slow<<<Bn, 64, 0, stream>>>(cs, cs2, prevG);
    }
    k_bounds<<<1, 32, 0, stream>>>(prevG, bps, bnds, segS, segE, nsegA, binoff);
    k_segmean<<<dim3(MAXSEG, Bn), 256, 0, stream>>>(sig, segS, segE, nsegA, segMean);
    k_spec<<<dim3(TB / 4, Bn), 256, 0, stream>>>(sig, segMean, segS, segE, nsegA, binoff, spec);
    k_stats<<<dim3(MAXSEG, Bn), 256, 0, stream>>>(spec, segS, segE, nsegA, binoff,
                                                  segPL, segDP, segBW, segNT);
    k_tokpref<<<1, 32, 0, stream>>>(nsegA, segNT, tokoff, ntokA);
    if (MT > 0)
        k_fill<<<dim3(MT, Bn), 256, 0, stream>>>(x, segS, segE, segPL, segDP, segBW,
                                                 nsegA, tokoff, ntokA, out, MT);
}

// Round 2
// 1464.315 us; speedup vs baseline: 1.1280x; 1.1280x over previous
//
#include <hip/hip_runtime.h>
#include <math.h>

#define Bn 32
#define Cn 32
#define Ln 16384
#define NF 511      // number of spectrogram frames
#define NB 33       // rfft bins of 64-pt window
#define MAXSEG 512
#define TB 8192     // total spectral bins per batch (sum of nf over segments = L/2)
#define PEN 5.0

// ---------------- sig = x.mean(axis=channels), float32 sequential (numpy axis-0 reduce order)
__global__ void k_sig(const float* __restrict__ x, float* __restrict__ sig) {
    int idx = blockIdx.x * 256 + threadIdx.x;
    if (idx >= Bn * Ln) return;
    int b = idx >> 14;
    int t = idx & (Ln - 1);
    const float* p = x + ((size_t)b * Cn) * Ln + t;
    float a = p[0];
    #pragma unroll
    for (int c = 1; c < Cn; c++) a += p[(size_t)c * Ln];
    sig[idx] = a / 32.0f;
}

// ---------------- frame means: numpy scalar pairwise 8-accumulator pattern, n=64, float32
__global__ void k_fmean(const float* __restrict__ sig, float* __restrict__ fm) {
    int idx = blockIdx.x * 256 + threadIdx.x;
    if (idx >= Bn * NF) return;
    int b = idx / NF, f = idx - b * NF;
    const float* a = sig + b * Ln + f * 32;
    float r[8];
    #pragma unroll
    for (int j = 0; j < 8; j++) r[j] = a[j];
    #pragma unroll
    for (int base = 8; base < 64; base += 8)
        #pragma unroll
        for (int j = 0; j < 8; j++) r[j] += a[base + j];
    float res = ((r[0] + r[1]) + (r[2] + r[3])) + ((r[4] + r[5]) + (r[6] + r[7]));
    fm[idx] = res / 64.0f;
}

// ---------------- feats = log(|rfft(hann * (frame - mean))|^2 + 1e-8), double
__global__ void k_feats(const float* __restrict__ sig, const float* __restrict__ fm,
                        double* __restrict__ feats) {
    __shared__ double v[64], ct[64], stb[64];
    int bf = blockIdx.x;
    int b = bf / NF, f = bf - b * NF;
    int i = threadIdx.x;  // 0..63
    double ang = (2.0 * M_PI * (double)i) / 64.0;
    double sn, cx;
    sincos(ang, &sn, &cx);
    ct[i] = cx; stb[i] = sn;
    int n2 = 2 * i - 63;                       // np.hanning: arange(1-M, M, 2)
    double w = 0.5 + 0.5 * cos((M_PI * (double)n2) / 63.0);
    float m = fm[bf];
    v[i] = (double)(sig[b * Ln + f * 32 + i] - m) * w;   // f32 subtract, f64 window mult
    __syncthreads();
    if (i < NB) {
        double re = 0.0, im = 0.0;
        for (int t = 0; t < 64; t++) {
            int j = (t * i) & 63;
            re += v[t] * ct[j];
            im += v[t] * stb[j];
        }
        double spec = re * re + im * im;
        feats[(size_t)bf * NB + i] = log(spec + 1e-8);
    }
}

// ---------------- cs / cs2 cumsums (sequential double, numpy cumsum order)
__global__ void k_cumsum(const double* __restrict__ feats, double* __restrict__ cs,
                         double* __restrict__ cs2) {
    int idx = blockIdx.x * 256 + threadIdx.x;
    if (idx >= Bn * NB) return;
    int b = idx / NB, d = idx - b * NB;
    const double* fp = feats + (size_t)b * NF * NB + d;
    double* c1 = cs + (size_t)b * 512 * NB + d;
    double* c2 = cs2 + (size_t)b * 512 * NB + d;
    double a1 = 0.0, a2 = 0.0;
    c1[0] = 0.0; c2[0] = 0.0;
    for (int t = 0; t < NF; t++) {
        double vv = fp[(size_t)t * NB];
        a1 += vv;
        a2 += vv * vv;
        c1[(size_t)(t + 1) * NB] = a1;
        c2[(size_t)(t + 1) * NB] = a2;
    }
}

// ---------------- precompute cost(c,t) for all pairs, massively parallel, exact numpy op order
__global__ __launch_bounds__(256) void k_cost(const double* __restrict__ cs,
                                              const double* __restrict__ cs2,
                                              double* __restrict__ costM) {
    int t = blockIdx.x + 1;   // 1..NF
    int b = blockIdx.y;
    const double* c1 = cs + (size_t)b * 512 * NB;
    const double* c2 = cs2 + (size_t)b * 512 * NB;
    __shared__ double sct1[NB], sct2[NB];
    if (threadIdx.x < NB) {
        sct1[threadIdx.x] = c1[(size_t)t * NB + threadIdx.x];
        sct2[threadIdx.x] = c2[(size_t)t * NB + threadIdx.x];
    }
    __syncthreads();
    double* outp = costM + ((size_t)b * 512 + (size_t)t) * 512;
    for (int c = threadIdx.x; c < t; c += 256) {
        double nn = (double)(t - c);
        const double* p1 = c1 + (size_t)c * NB;
        const double* p2 = c2 + (size_t)c * NB;
        // numpy pairwise sum over 33 dims: 8 accumulators + remainder
        double r[8];
        #pragma unroll
        for (int j = 0; j < 8; j++) {
            double ss = sct1[j] - p1[j]; double s2 = sct2[j] - p2[j];
            r[j] = s2 - ss * ss / nn;
        }
        #pragma unroll
        for (int base = 8; base < 32; base += 8)
            #pragma unroll
            for (int j = 0; j < 8; j++) {
                int d = base + j;
                double ss = sct1[d] - p1[d]; double s2 = sct2[d] - p2[d];
                r[j] += s2 - ss * ss / nn;
            }
        double res = ((r[0] + r[1]) + (r[2] + r[3])) + ((r[4] + r[5]) + (r[6] + r[7]));
        { double ss = sct1[32] - p1[32]; double s2 = sct2[32] - p2[32]; res += s2 - ss * ss / nn; }
        outp[c] = res;
    }
}

// ---------------- DPP-based wave-64 min reduce for f64 (VALU pipe, no LDS/ds_bpermute).
// Classic GCN sequence: row_shr 1/2/4/8 then row_bcast15, row_bcast31 -> full min in
// lane 63; broadcast back via v_readlane (SGPR, uniform). Doubles are moved as two
// coherent 32-bit halves with bound_ctrl=false and old=self, so lanes with an invalid
// DPP source reduce with their own value (identity for min).
template <int CTRL>
__device__ __forceinline__ double dpp_min_stage(double v) {
    int lo = __double2loint(v), hi = __double2hiint(v);
    int slo = __builtin_amdgcn_update_dpp(lo, lo, CTRL, 0xF, 0xF, false);
    int shi = __builtin_amdgcn_update_dpp(hi, hi, CTRL, 0xF, 0xF, false);
    double o = __hiloint2double(shi, slo);
    return (o < v) ? o : v;
}
__device__ __forceinline__ double wave_min_f64(double v) {
    v = dpp_min_stage<0x111>(v);   // row_shr:1
    v = dpp_min_stage<0x112>(v);   // row_shr:2
    v = dpp_min_stage<0x114>(v);   // row_shr:4
    v = dpp_min_stage<0x118>(v);   // row_shr:8  -> lane 16r+15 = min(row r)
    v = dpp_min_stage<0x142>(v);   // row_bcast:15 -> lane31=min(r0,r1), lane63=min(r2,r3)
    v = dpp_min_stage<0x143>(v);   // row_bcast:31 -> lane63 = global min
    int lo = __builtin_amdgcn_readlane(__double2loint(v), 63);
    int hi = __builtin_amdgcn_readlane(__double2hiint(v), 63);
    return __hiloint2double(hi, lo);
}

// ---------------- PELT DP with precomputed costs: one wave/batch, bitmask candidates,
// Fc in registers, depth-4 pipelined row prefetch. The per-step argmin is split:
// (1) value-only wave min via DPP (VALU latency, replacing the ds_bpermute butterfly
//     that dominated at ~2000 cy/step), (2) first-occurrence index recovery via 8
//     v_cmp_eq_f64 ballots (descending p, lowest set bit) -- wave-uniform, matches
//     numpy argmin tie-breaking since cands are ascending in c.
__global__ __launch_bounds__(64, 1) void k_pelt(const double* __restrict__ costM,
                                                int* __restrict__ prevG) {
    int b = blockIdx.x;
    int lane = threadIdx.x;
    const double* cm = costM + (size_t)b * 512 * 512;

    unsigned long long cmask[8] = {1ull, 0, 0, 0, 0, 0, 0, 0};
    double fcreg[8];   // Fc[p*64 + lane], owned by this lane
    #pragma unroll
    for (int p = 0; p < 8; p++) fcreg[p] = INFINITY;
    if (lane == 0) fcreg[0] = -PEN;   // Fc[0]

    // one DP step for row t held in cur[8] (all cur indices compile-time after unroll)
    auto step = [&](int t, double (&cur)[8]) {
        double vals[8];
        #pragma unroll
        for (int p = 0; p < 8; p++) {
            bool isc = ((cmask[p] >> lane) & 1ull) != 0ull;
            vals[p] = isc ? (fcreg[p] + cur[p] + PEN) : INFINITY;
        }
        // local min over the 8 per-lane slots (value only, no index)
        double m0 = vals[0] < vals[1] ? vals[0] : vals[1];
        double m1 = vals[2] < vals[3] ? vals[2] : vals[3];
        double m2 = vals[4] < vals[5] ? vals[4] : vals[5];
        double m3 = vals[6] < vals[7] ? vals[6] : vals[7];
        double m4 = m0 < m1 ? m0 : m1;
        double m5 = m2 < m3 ? m2 : m3;
        double lmin = m4 < m5 ? m4 : m5;
        // wave min (DPP, VALU pipe), broadcast to all lanes
        double bmin = wave_min_f64(lmin);
        // first-occurrence argmin: lowest c with vals == bmin. c = (p<<6)+lane, so
        // descending-p overwrite + lowest set lane bit = smallest c. Wave-uniform.
        int bc = 0;
        #pragma unroll
        for (int p = 7; p >= 0; p--) {
            unsigned long long m = __ballot(vals[p] == bmin);
            if (m != 0ull) bc = (p << 6) + (__ffsll(m) - 1);
        }
        if (lane == 0) prevG[b * 512 + t] = bc;
        // latch Fc[t] into the owning lane's register (static index form)
        #pragma unroll
        for (int p = 0; p < 8; p++)
            if (p == (t >> 6) && lane == (t & 63)) fcreg[p] = bmin;
        // prune candidates (bitmask &= keep), then add candidate t (static index form)
        double thr = bmin + PEN;
        #pragma unroll
        for (int p = 0; p < 8; p++) {
            unsigned long long keep = __ballot(vals[p] <= thr);
            cmask[p] &= keep;
        }
        int tp = t >> 6;
        unsigned long long tbit = 1ull << (t & 63);
        #pragma unroll
        for (int p = 0; p < 8; p++)
            if (p == tp) cmask[p] |= tbit;
    };

    // preload rows 1..4
    double r0[8], r1[8], r2[8], r3[8];
    #pragma unroll
    for (int p = 0; p < 8; p++) {
        r0[p] = cm[(size_t)1 * 512 + (p << 6) + lane];
        r1[p] = cm[(size_t)2 * 512 + (p << 6) + lane];
        r2[p] = cm[(size_t)3 * 512 + (p << 6) + lane];
        r3[p] = cm[(size_t)4 * 512 + (p << 6) + lane];
    }

    int t = 1;
    for (; t + 3 <= NF - 3; t += 4) {          // groups t..t+3 for t = 1,5,...,505 (covers 1..508)
        double n0[8], n1[8], n2[8], n3[8];
        int q0 = t + 4, q1 = t + 5, q2 = t + 6, q3 = t + 7;
        if (q3 > NF) q3 = NF;                  // only q3 can exceed NF (clamped dup, unused in tail)
        #pragma unroll
        for (int p = 0; p < 8; p++) {
            n0[p] = cm[(size_t)q0 * 512 + (p << 6) + lane];
            n1[p] = cm[(size_t)q1 * 512 + (p << 6) + lane];
            n2[p] = cm[(size_t)q2 * 512 + (p << 6) + lane];
            n3[p] = cm[(size_t)q3 * 512 + (p << 6) + lane];
        }
        step(t, r0); step(t + 1, r1); step(t + 2, r2); step(t + 3, r3);
        #pragma unroll
        for (int p = 0; p < 8; p++) { r0[p] = n0[p]; r1[p] = n1[p]; r2[p] = n2[p]; r3[p] = n3[p]; }
    }
    // tail: t = 509, 510, 511 (rows already resident in r0..r2)
    if (t     <= NF) step(t,     r0);
    if (t + 1 <= NF) step(t + 1, r1);
    if (t + 2 <= NF) step(t + 2, r2);
    if (t + 3 <= NF) step(t + 3, r3);
}

// ---------------- fallback PELT (round-2 version) if workspace can't hold cost matrix
__global__ __launch_bounds__(64) void k_pelt_slow(const double* __restrict__ cs,
                                                  const double* __restrict__ cs2,
                                                  int* __restrict__ prevG) {
    __shared__ double sFc[512];
    __shared__ double sVal[512];
    __shared__ unsigned short sCand[512];
    int b = blockIdx.x;
    int lane = threadIdx.x;
    const double* c1 = cs + (size_t)b * 512 * NB;
    const double* c2 = cs2 + (size_t)b * 512 * NB;
    if (lane == 0) { sFc[0] = -PEN; sCand[0] = 0; }
    __syncthreads();
    int ncand = 1;
    for (int t = 1; t <= NF; t++) {
        const double* ct1 = c1 + (size_t)t * NB;
        const double* ct2 = c2 + (size_t)t * NB;
        int passes = (ncand + 63) >> 6;
        double bmv = INFINITY;
        int bmi = 0x7fffffff;
        for (int p = 0; p < passes; p++) {
            int slot = (p << 6) + lane;
            double val = INFINITY;
            if (slot < ncand) {
                int cc = sCand[slot];
                double nn = (double)(t - cc);
                const double* p1 = c1 + (size_t)cc * NB;
                const double* p2 = c2 + (size_t)cc * NB;
                double r[8];
                #pragma unroll
                for (int j = 0; j < 8; j++) {
                    double ss = ct1[j] - p1[j]; double s2 = ct2[j] - p2[j];
                    r[j] = s2 - ss * ss / nn;
                }
                #pragma unroll
                for (int base = 8; base < 32; base += 8)
                    #pragma unroll
                    for (int j = 0; j < 8; j++) {
                        int d = base + j;
                        double ss = ct1[d] - p1[d]; double s2 = ct2[d] - p2[d];
                        r[j] += s2 - ss * ss / nn;
                    }
                double res = ((r[0] + r[1]) + (r[2] + r[3])) + ((r[4] + r[5]) + (r[6] + r[7]));
                { double ss = ct1[32] - p1[32]; double s2 = ct2[32] - p2[32]; res += s2 - ss * ss / nn; }
                val = sFc[cc] + res + PEN;
                if (val < bmv) { bmv = val; bmi = slot; }
            }
            sVal[slot] = val;
        }
        #pragma unroll
        for (int off = 1; off < 64; off <<= 1) {
            double ov = __shfl_xor(bmv, off);
            int oi = __shfl_xor(bmi, off);
            if (ov < bmv || (ov == bmv && oi < bmi)) { bmv = ov; bmi = oi; }
        }
        double thr = bmv + PEN;
        if (lane == 0) {
            sFc[t] = bmv;
            prevG[b * 512 + t] = (int)sCand[bmi];
        }
        __syncthreads();
        int base = 0;
        for (int p = 0; p < passes; p++) {
            int slot = (p << 6) + lane;
            int cc = (slot < ncand) ? (int)sCand[slot] : 0;
            bool keep = (slot < ncand) && (sVal[slot] <= thr);
            unsigned long long mask = __ballot(keep);
            if (keep) sCand[base + __popcll(mask & ((1ull << lane) - 1ull))] = (unsigned short)cc;
            base += (int)__popcll(mask);
        }
        if (lane == 0) sCand[base] = (unsigned short)t;
        ncand = base + 1;
        __syncthreads();
    }
}

// ---------------- backtrack + bounds + segment table + bin offsets (1 thread per batch)
__global__ void k_bounds(const int* __restrict__ prevG, int* __restrict__ bps, int* __restrict__ bnds,
                         int* __restrict__ segS, int* __restrict__ segE, int* __restrict__ nsegA,
                         int* __restrict__ binoff) {
    int b = threadIdx.x;
    if (b >= Bn) return;
    const int* pv = prevG + b * 512;
    int* bp = bps + b * 512;
    int* bd = bnds + b * 520;
    int cnt = 0, t = NF;
    while (t > 0) { bp[cnt++] = t; t = pv[t]; }
    int nb = 1; bd[0] = 0;
    for (int i = cnt - 1; i >= 1; --i) {
        int k = bp[i];
        int bb = 32 * k;
        if (bb > Ln) bb = Ln;
        if (bb - bd[nb - 1] >= 8) bd[nb++] = bb;
    }
    if (Ln - bd[nb - 1] < 8 && nb > 1) nb--;
    bd[nb++] = Ln;
    int ns = nb - 1;
    nsegA[b] = ns;
    int off = 0;
    for (int j = 0; j < ns; j++) {
        int s = bd[j], e = bd[j + 1];
        segS[b * 512 + j] = s; segE[b * 512 + j] = e;
        binoff[b * 513 + j] = off;
        off += (e - s) >> 1;
    }
    binoff[b * 513 + ns] = off;
}

// ---------------- per-segment mean (double)
__global__ void k_segmean(const float* __restrict__ sig, const int* __restrict__ segS,
                          const int* __restrict__ segE, const int* __restrict__ nsegA,
                          double* __restrict__ segMean) {
    __shared__ double red[256];
    int b = blockIdx.y, j = blockIdx.x;
    if (j >= nsegA[b]) return;
    int s = segS[b * 512 + j], e = segE[b * 512 + j];
    double acc = 0.0;
    for (int i = s + threadIdx.x; i < e; i += 256) acc += (double)sig[b * Ln + i];
    red[threadIdx.x] = acc;
    __syncthreads();
    for (int st = 128; st >= 1; st >>= 1) {
        if (threadIdx.x < st) red[threadIdx.x] += red[threadIdx.x + st];
        __syncthreads();
    }
    if (threadIdx.x == 0) segMean[b * 512 + j] = red[0] / (double)(e - s);
}

// ---------------- segment DFT: one wave per (batch, bin-slot), rotation recurrence in double
__global__ __launch_bounds__(256) void k_spec(const float* __restrict__ sig,
                                              const double* __restrict__ segMean,
                                              const int* __restrict__ segS, const int* __restrict__ segE,
                                              const int* __restrict__ nsegA, const int* __restrict__ binoff,
                                              double* __restrict__ spec) {
    int b = blockIdx.y;
    int wv = threadIdx.x >> 6, lane = threadIdx.x & 63;
    int slot = blockIdx.x * 4 + wv;
    int ns = nsegA[b];
    const int* off = binoff + b * 513;
    if (slot >= off[ns]) return;
    int lo = 0, hi = ns - 1;
    while (lo < hi) { int mid = (lo + hi + 1) >> 1; if (off[mid] <= slot) lo = mid; else hi = mid - 1; }
    int j = lo;
    int s = segS[b * 512 + j], e = segE[b * 512 + j], n = e - s;
    int k = slot - off[j] + 1;
    float m32 = (float)segMean[b * 512 + j];
    long j0 = ((long)lane * (long)k) % (long)n;
    long js = (64L * (long)k) % (long)n;
    double a0 = (2.0 * M_PI * (double)j0) / (double)n;
    double as = (2.0 * M_PI * (double)js) / (double)n;
    double cr, sr, cb, sb;
    sincos(a0, &sr, &cr);
    sincos(as, &sb, &cb);
    double re = 0.0, im = 0.0;
    const float* sp = sig + b * Ln + s;
    for (int tt = lane; tt < n; tt += 64) {
        double v = (double)(sp[tt] - m32);
        re += v * cr;
        im += v * sr;
        double nc = cr * cb - sr * sb;
        sr = sr * cb + cr * sb;
        cr = nc;
    }
    #pragma unroll
    for (int o = 32; o >= 1; o >>= 1) { re += __shfl_down(re, o); im += __shfl_down(im, o); }
    if (lane == 0) spec[(size_t)b * TB + slot] = re * re + im * im;
}

// ---------------- per-segment stats
__global__ void k_stats(const double* __restrict__ spec, const int* __restrict__ segS,
                        const int* __restrict__ segE, const int* __restrict__ nsegA,
                        const int* __restrict__ binoff, int* __restrict__ segPL,
                        double* __restrict__ segDP, double* __restrict__ segBW,
                        int* __restrict__ segNT) {
    __shared__ double rv[256]; __shared__ int ri[256];
    __shared__ double rt[256], rs[256];
    __shared__ double sC, sTot;
    int b = blockIdx.y, j = blockIdx.x;
    if (j >= nsegA[b]) return;
    int s = segS[b * 512 + j], e = segE[b * 512 + j], n = e - s, nf = n >> 1;
    const double* base = spec + (size_t)b * TB + binoff[b * 513 + j];
    int tid = threadIdx.x;
    double mv = -INFINITY; int mi = 0x7fffffff; double tot = 0.0, s1 = 0.0;
    for (int i = tid; i < nf; i += 256) {
        double vv = base[i];
        double f = (double)(i + 1) / (double)nf;
        tot += vv; s1 += vv * f;
        if (vv > mv) { mv = vv; mi = i; }
    }
    rv[tid] = mv; ri[tid] = mi; rt[tid] = tot; rs[tid] = s1;
    __syncthreads();
    for (int st = 128; st >= 1; st >>= 1) {
        if (tid < st) {
            double ov = rv[tid + st]; int oi = ri[tid + st];
            if (ov > rv[tid] || (ov == rv[tid] && oi < ri[tid])) { rv[tid] = ov; ri[tid] = oi; }
            rt[tid] += rt[tid + st]; rs[tid] += rs[tid + st];
        }
        __syncthreads();
    }
    if (tid == 0) { sTot = rt[0]; sC = rs[0] / rt[0]; }
    __syncthreads();
    double c = sC, totv = sTot;
    double s2 = 0.0;
    for (int i = tid; i < nf; i += 256) {
        double f = (double)(i + 1) / (double)nf;
        double d = f - c;
        s2 += base[i] * d * d;
    }
    rt[tid] = s2;
    __syncthreads();
    for (int st = 128; st >= 1; st >>= 1) {
        if (tid < st) rt[tid] += rt[tid + st];
        __syncthreads();
    }
    if (tid == 0) {
        double dp, bw;
        if (n < 4) { dp = (double)(n > 0 ? n : 1); bw = 0.0; }
        else if (!(totv > 0.0)) { dp = (double)n; bw = 0.0; }
        else { int kk = ri[0] + 1; dp = (double)n / (double)kk; bw = sqrt(rt[0] / totv); }
        double raw = 1.0 * dp / (1.0 + 1.0 * bw);
        double rr = rint(raw / 2.0);          // Python round(): half-to-even
        long pl = 2L * (long)rr;
        if (pl < 8) pl = 8;
        if (pl > 64) pl = 64;
        int nfull = n / (int)pl;
        int ntok = nfull + ((nfull * (int)pl < n) ? 1 : 0);
        segPL[b * 512 + j] = (int)pl; segDP[b * 512 + j] = dp;
        segBW[b * 512 + j] = bw; segNT[b * 512 + j] = ntok;
    }
}

// ---------------- token prefix offsets per batch
__global__ void k_tokpref(const int* __restrict__ nsegA, const int* __restrict__ segNT,
                          int* __restrict__ tokoff, int* __restrict__ ntokA) {
    int b = threadIdx.x;
    if (b >= Bn) return;
    int ns = nsegA[b]; int off = 0;
    for (int j = 0; j < ns; j++) { tokoff[b * 513 + j] = off; off += segNT[b * 512 + j]; }
    tokoff[b * 513 + ns] = off;
    ntokA[b] = off;
}

// ---------------- fill all outputs: one block per (batch, token)
__global__ __launch_bounds__(256) void k_fill(const float* __restrict__ x,
                                              const int* __restrict__ segS, const int* __restrict__ segE,
                                              const int* __restrict__ segPL, const double* __restrict__ segDP,
                                              const double* __restrict__ segBW, const int* __restrict__ nsegA,
                                              const int* __restrict__ tokoff, const int* __restrict__ ntokA,
                                              float* __restrict__ out, int MT) {
    int b = blockIdx.y, tok = blockIdx.x;
    int nt = ntokA[b];
    if (tok >= nt) return;
    int ns = nsegA[b];
    const int* toff = tokoff + b * 513;
    int lo = 0, hi = ns - 1;
    while (lo < hi) { int mid = (lo + hi + 1) >> 1; if (toff[mid] <= tok) lo = mid; else hi = mid - 1; }
    int j = lo;
    int s = segS[b * 512 + j], e = segE[b * 512 + j], pl = segPL[b * 512 + j];
    int idx = tok - toff[j];
    int nfull = (e - s) / pl;
    int st, en;
    if (idx < nfull) { st = s + idx * pl; en = st + pl; }
    else { st = s + nfull * pl; en = e; }
    int ilen = en - st;
    float scale = (float)ilen / 16.0f;
    int tid = threadIdx.x;
    size_t pbase = ((size_t)(b * MT + tok)) * (Cn * 16);
    const float* xb = x + (size_t)b * Cn * Ln;
    #pragma unroll
    for (int r = 0; r < 2; r++) {
        int eidx = tid + r * 256;
        int c = eidx >> 4, jo = eidx & 15;
        float coords = ((float)jo + 0.5f) * scale - 0.5f;
        if (coords < 0.0f) coords = 0.0f;
        float mx = (float)(ilen - 1);
        if (coords > mx) coords = mx;
        int l2 = (int)floorf(coords);
        int h2 = l2 + 1;
        if (h2 > ilen - 1) h2 = ilen - 1;
        float w = coords - (float)l2;
        const float* xc = xb + (size_t)c * Ln + st;
        out[pbase + eidx] = xc[l2] * (1.0f - w) + xc[h2] * w;
    }
    if (tid == 0) {
        size_t BT = (size_t)Bn * MT;
        size_t o_mask = BT * 512;
        size_t pos = (size_t)b * MT + tok;
        out[o_mask + pos] = 1.0f;                                  // mask
        out[o_mask + BT + pos] = (float)st;                        // start
        out[o_mask + 2 * BT + pos] = (float)en;                    // end
        out[o_mask + 3 * BT + pos] = (((float)st + (float)en) - 1.0f) * 0.5f / 16383.0f;  // center
        out[o_mask + 4 * BT + pos] = (float)(en - st) / 16384.0f;  // span
        double dp = segDP[b * 512 + j], bwv = segBW[b * 512 + j];
        size_t o_rg = o_mask + 5 * BT;
        out[o_rg + pos * 3 + 0] = (float)(dp / 16384.0);
        out[o_rg + pos * 3 + 1] = (float)bwv;
        out[o_rg + pos * 3 + 2] = (float)((double)(e - s) / 16384.0);
        if (tok == 0) out[o_mask + 8 * BT + b] = (float)nt;        // n_tok
    }
}

extern "C" void kernel_launch(void* const* d_in, const int* in_sizes, int n_in,
                              void* d_out, int out_size, void* d_ws, size_t ws_size,
                              hipStream_t stream) {
    (void)in_sizes; (void)n_in;
    const float* x = (const float*)d_in[0];
    float* out = (float*)d_out;
    char* ws = (char*)d_ws;
    size_t o = 0;
    auto alloc = [&](size_t bytes) -> char* {
        char* r = ws + o;
        o = (o + bytes + 511) & ~(size_t)511;
        return r;
    };
    float* sig = (float*)alloc((size_t)Bn * Ln * 4);
    float* fm = (float*)alloc((size_t)Bn * NF * 4);
    double* feats = (double*)alloc((size_t)Bn * NF * NB * 8);
    double* cs = (double*)alloc((size_t)Bn * 512 * NB * 8);
    double* cs2 = (double*)alloc((size_t)Bn * 512 * NB * 8);
    int* prevG = (int*)alloc((size_t)Bn * 512 * 4);
    int* bps = (int*)alloc((size_t)Bn * 512 * 4);
    int* bnds = (int*)alloc((size_t)Bn * 520 * 4);
    int* nsegA = (int*)alloc((size_t)Bn * 4);
    int* segS = (int*)alloc((size_t)Bn * 512 * 4);
    int* segE = (int*)alloc((size_t)Bn * 512 * 4);
    int* segPL = (int*)alloc((size_t)Bn * 512 * 4);
    int* segNT = (int*)alloc((size_t)Bn * 512 * 4);
    double* segDP = (double*)alloc((size_t)Bn * 512 * 8);
    double* segBW = (double*)alloc((size_t)Bn * 512 * 8);
    double* segMean = (double*)alloc((size_t)Bn * 512 * 8);
    int* binoff = (int*)alloc((size_t)Bn * 513 * 4);
    int* tokoff = (int*)alloc((size_t)Bn * 513 * 4);
    int* ntokA = (int*)alloc((size_t)Bn * 4);
    double* spec = (double*)alloc((size_t)Bn * TB * 8);
    size_t costBytes = (size_t)Bn * 512 * 512 * 8;   // 67 MB
    double* costM = (double*)alloc(costBytes);
    bool haveCost = (o <= ws_size);

    int MT = (out_size / Bn - 1) / 520;   // out_size = Bn*(MT*520 + 1)

    hipMemsetAsync(d_out, 0, (size_t)out_size * 4, stream);
    k_sig<<<(Bn * Ln + 255) / 256, 256, 0, stream>>>(x, sig);
    k_fmean<<<(Bn * NF + 255) / 256, 256, 0, stream>>>(sig, fm);
    k_feats<<<Bn * NF, 64, 0, stream>>>(sig, fm, feats);
    k_cumsum<<<(Bn * NB + 255) / 256, 256, 0, stream>>>(feats, cs, cs2);
    if (haveCost) {
        k_cost<<<dim3(NF, Bn), 256, 0, stream>>>(cs, cs2, costM);
        k_pelt<<<Bn, 64, 0, stream>>>(costM, prevG);
    } else {
        k_pelt_slow<<<Bn, 64, 0, stream>>>(cs, cs2, prevG);
    }
    k_bounds<<<1, 32, 0, stream>>>(prevG, bps, bnds, segS, segE, nsegA, binoff);
    k_segmean<<<dim3(MAXSEG, Bn), 256, 0, stream>>>(sig, segS, segE, nsegA, segMean);
    k_spec<<<dim3(TB / 4, Bn), 256, 0, stream>>>(sig, segMean, segS, segE, nsegA, binoff, spec);
    k_stats<<<dim3(MAXSEG, Bn), 256, 0, stream>>>(spec, segS, segE, nsegA, binoff,
                                                  segPL, segDP, segBW, segNT);
    k_tokpref<<<1, 32, 0, stream>>>(nsegA, segNT, tokoff, ntokA);
    if (MT > 0)
        k_fill<<<dim3(MT, Bn), 256, 0, stream>>>(x, segS, segE, segPL, segDP, segBW,
                                                 nsegA, tokoff, ntokA, out, MT);
}

// Round 4
// 1311.276 us; speedup vs baseline: 1.2597x; 1.1167x over previous
//
#include <hip/hip_runtime.h>
#include <math.h>

#define Bn 32
#define Cn 32
#define Ln 16384
#define NF 511      // number of spectrogram frames
#define NB 33       // rfft bins of 64-pt window
#define MAXSEG 512
#define TB 8192     // total spectral bins per batch (sum of nf over segments = L/2)
#define PEN 5.0

// ---------------- sig = x.mean(axis=channels), float32 sequential (numpy axis-0 reduce order)
__global__ void k_sig(const float* __restrict__ x, float* __restrict__ sig) {
    int idx = blockIdx.x * 256 + threadIdx.x;
    if (idx >= Bn * Ln) return;
    int b = idx >> 14;
    int t = idx & (Ln - 1);
    const float* p = x + ((size_t)b * Cn) * Ln + t;
    float a = p[0];
    #pragma unroll
    for (int c = 1; c < Cn; c++) a += p[(size_t)c * Ln];
    sig[idx] = a / 32.0f;
}

// ---------------- frame means: numpy scalar pairwise 8-accumulator pattern, n=64, float32
__global__ void k_fmean(const float* __restrict__ sig, float* __restrict__ fm) {
    int idx = blockIdx.x * 256 + threadIdx.x;
    if (idx >= Bn * NF) return;
    int b = idx / NF, f = idx - b * NF;
    const float* a = sig + b * Ln + f * 32;
    float r[8];
    #pragma unroll
    for (int j = 0; j < 8; j++) r[j] = a[j];
    #pragma unroll
    for (int base = 8; base < 64; base += 8)
        #pragma unroll
        for (int j = 0; j < 8; j++) r[j] += a[base + j];
    float res = ((r[0] + r[1]) + (r[2] + r[3])) + ((r[4] + r[5]) + (r[6] + r[7]));
    fm[idx] = res / 64.0f;
}

// ---------------- feats = log(|rfft(hann * (frame - mean))|^2 + 1e-8), double
__global__ void k_feats(const float* __restrict__ sig, const float* __restrict__ fm,
                        double* __restrict__ feats) {
    __shared__ double v[64], ct[64], stb[64];
    int bf = blockIdx.x;
    int b = bf / NF, f = bf - b * NF;
    int i = threadIdx.x;  // 0..63
    double ang = (2.0 * M_PI * (double)i) / 64.0;
    double sn, cx;
    sincos(ang, &sn, &cx);
    ct[i] = cx; stb[i] = sn;
    int n2 = 2 * i - 63;                       // np.hanning: arange(1-M, M, 2)
    double w = 0.5 + 0.5 * cos((M_PI * (double)n2) / 63.0);
    float m = fm[bf];
    v[i] = (double)(sig[b * Ln + f * 32 + i] - m) * w;   // f32 subtract, f64 window mult
    __syncthreads();
    if (i < NB) {
        double re = 0.0, im = 0.0;
        for (int t = 0; t < 64; t++) {
            int j = (t * i) & 63;
            re += v[t] * ct[j];
            im += v[t] * stb[j];
        }
        double spec = re * re + im * im;
        feats[(size_t)bf * NB + i] = log(spec + 1e-8);
    }
}

// ---------------- cs / cs2 cumsums (sequential double, numpy cumsum order)
__global__ void k_cumsum(const double* __restrict__ feats, double* __restrict__ cs,
                         double* __restrict__ cs2) {
    int idx = blockIdx.x * 256 + threadIdx.x;
    if (idx >= Bn * NB) return;
    int b = idx / NB, d = idx - b * NB;
    const double* fp = feats + (size_t)b * NF * NB + d;
    double* c1 = cs + (size_t)b * 512 * NB + d;
    double* c2 = cs2 + (size_t)b * 512 * NB + d;
    double a1 = 0.0, a2 = 0.0;
    c1[0] = 0.0; c2[0] = 0.0;
    for (int t = 0; t < NF; t++) {
        double vv = fp[(size_t)t * NB];
        a1 += vv;
        a2 += vv * vv;
        c1[(size_t)(t + 1) * NB] = a1;
        c2[(size_t)(t + 1) * NB] = a2;
    }
}

// ---------------- precompute cost(c,t) for all pairs, massively parallel, exact numpy op order
__global__ __launch_bounds__(256) void k_cost(const double* __restrict__ cs,
                                              const double* __restrict__ cs2,
                                              double* __restrict__ costM) {
    int t = blockIdx.x + 1;   // 1..NF
    int b = blockIdx.y;
    const double* c1 = cs + (size_t)b * 512 * NB;
    const double* c2 = cs2 + (size_t)b * 512 * NB;
    __shared__ double sct1[NB], sct2[NB];
    if (threadIdx.x < NB) {
        sct1[threadIdx.x] = c1[(size_t)t * NB + threadIdx.x];
        sct2[threadIdx.x] = c2[(size_t)t * NB + threadIdx.x];
    }
    __syncthreads();
    double* outp = costM + ((size_t)b * 512 + (size_t)t) * 512;
    for (int c = threadIdx.x; c < t; c += 256) {
        double nn = (double)(t - c);
        const double* p1 = c1 + (size_t)c * NB;
        const double* p2 = c2 + (size_t)c * NB;
        // numpy pairwise sum over 33 dims: 8 accumulators + remainder
        double r[8];
        #pragma unroll
        for (int j = 0; j < 8; j++) {
            double ss = sct1[j] - p1[j]; double s2 = sct2[j] - p2[j];
            r[j] = s2 - ss * ss / nn;
        }
        #pragma unroll
        for (int base = 8; base < 32; base += 8)
            #pragma unroll
            for (int j = 0; j < 8; j++) {
                int d = base + j;
                double ss = sct1[d] - p1[d]; double s2 = sct2[d] - p2[d];
                r[j] += s2 - ss * ss / nn;
            }
        double res = ((r[0] + r[1]) + (r[2] + r[3])) + ((r[4] + r[5]) + (r[6] + r[7]));
        { double ss = sct1[32] - p1[32]; double s2 = sct2[32] - p2[32]; res += s2 - ss * ss / nn; }
        outp[c] = res;
    }
}

// ---------------- f64 helpers: DPP move and wave-64 min on the VALU pipe (v_min_f64).
// update_dpp with bound_ctrl=false and old=self: invalid-source lanes keep their own
// value, the identity for min.
template <int CTRL>
__device__ __forceinline__ double dpp_mov_f64(double v) {
    int lo = __double2loint(v), hi = __double2hiint(v);
    int slo = __builtin_amdgcn_update_dpp(lo, lo, CTRL, 0xF, 0xF, false);
    int shi = __builtin_amdgcn_update_dpp(hi, hi, CTRL, 0xF, 0xF, false);
    return __hiloint2double(shi, slo);
}
__device__ __forceinline__ double rl_f64(double v, int l) {
    int lo = __builtin_amdgcn_readlane(__double2loint(v), l);
    int hi = __builtin_amdgcn_readlane(__double2hiint(v), l);
    return __hiloint2double(hi, lo);
}
// 4 row_shr stages put each 16-lane row's min in lanes 15/31/47/63; combine via
// readlane (chain: 4 dpp-min stages + 2-level min tree), result wave-uniform.
__device__ __forceinline__ double wave_min_f64(double v) {
    v = fmin(v, dpp_mov_f64<0x111>(v));   // row_shr:1
    v = fmin(v, dpp_mov_f64<0x112>(v));   // row_shr:2
    v = fmin(v, dpp_mov_f64<0x114>(v));   // row_shr:4
    v = fmin(v, dpp_mov_f64<0x118>(v));   // row_shr:8
    double a = rl_f64(v, 15), b = rl_f64(v, 31);
    double c = rl_f64(v, 47), d = rl_f64(v, 63);
    return fmin(fmin(a, b), fmin(c, d));
}

// ---------------- one PELT DP step over NP active slots.
// Candidate representation: fcreg[p] (lane-owned Fc[p*64+lane]) is +INF for
// absent/pruned candidates -- no mask needed: INF + cost + PEN = INF, which loses
// every fmin and fails the ==bmin ballot. Garbage cost rows (c >= t, uninitialized)
// sit behind INF fcreg; a NaN produced by INF+garbage is ignored by
// v_min_f64 (minNum) and compares false in the ballot.
template <int NP>
__device__ __forceinline__ void pelt_step(int t, int lane, const double (&cur)[8],
                                          double (&fcreg)[8], int* __restrict__ prevOut) {
    double vals[NP];
    #pragma unroll
    for (int p = 0; p < NP; p++) vals[p] = fcreg[p] + cur[p] + PEN;   // (Fc+cost)+PEN, numpy order
    // balanced local min tree over NP slots
    double red[NP];
    #pragma unroll
    for (int p = 0; p < NP; p++) red[p] = vals[p];
    #pragma unroll
    for (int s = 1; s < NP; s <<= 1)
        #pragma unroll
        for (int p = 0; p + s < NP; p += 2 * s) red[p] = fmin(red[p], red[p + s]);
    double bmin = wave_min_f64(red[0]);
    // first-occurrence argmin: smallest c with vals == bmin (c = (p<<6)+lane).
    // Descending-p overwrite + lowest set lane bit = smallest c; wave-uniform.
    int bc = 0;
    #pragma unroll
    for (int p = NP - 1; p >= 0; p--) {
        unsigned long long m = __ballot(vals[p] == bmin);
        if (m != 0ull) bc = (p << 6) + (__ffsll(m) - 1);
    }
    if (lane == 0) prevOut[t] = bc;
    // prune: candidates with val > Fc[t]+PEN become +INF (absent lanes stay INF)
    double thr = bmin + PEN;
    #pragma unroll
    for (int p = 0; p < NP; p++)
        if (!(vals[p] <= thr)) fcreg[p] = INFINITY;
    // add candidate t: latch Fc[t]=bmin into its owning lane. Within phase K,
    // t>>6 is K except at the boundary step t=64(K+1) where it is K+1.
    #pragma unroll
    for (int p = NP - 1; p <= NP; p++)
        if (p < 8 && p == (t >> 6) && lane == (t & 63)) fcreg[p] = bmin;
}

// ---------------- one phase: t in [64K+1, min(64K+64, NF)], NP=K+1 active slots.
// Depth-2 register double-buffer (4 bufs x NP doubles <= 64 VGPRs even at NP=8, so
// the allocator can actually keep the pipeline -- the old depth-4 x 8-slot version
// needed 128+ VGPRs and was collapsed by regalloc, exposing L3 latency per group).
template <int K>
__device__ __forceinline__ void pelt_phase(const double* __restrict__ cm, int lane,
                                           double (&fcreg)[8], int* __restrict__ prevOut) {
    constexpr int NP = K + 1;
    const int t0 = 64 * K + 1;
    const int t1 = (64 * K + 64 < NF) ? (64 * K + 64) : NF;   // inclusive
    double r0[8], r1[8], n0[8], n1[8];
    #pragma unroll
    for (int p = 0; p < NP; p++) {
        r0[p] = cm[(size_t)t0 * 512 + (p << 6) + lane];
        r1[p] = cm[(size_t)(t0 + 1) * 512 + (p << 6) + lane];   // t0+1 <= 450 <= NF always
    }
    int t = t0;
    for (; t + 1 <= t1; t += 2) {
        int q0 = t + 2, q1 = t + 3;
        if (q0 > NF) q0 = NF;
        if (q1 > NF) q1 = NF;
        #pragma unroll
        for (int p = 0; p < NP; p++) {
            n0[p] = cm[(size_t)q0 * 512 + (p << 6) + lane];
            n1[p] = cm[(size_t)q1 * 512 + (p << 6) + lane];
        }
        pelt_step<NP>(t, lane, r0, fcreg, prevOut);
        pelt_step<NP>(t + 1, lane, r1, fcreg, prevOut);
        #pragma unroll
        for (int p = 0; p < NP; p++) { r0[p] = n0[p]; r1[p] = n1[p]; }
    }
    if (t <= t1) pelt_step<NP>(t, lane, r0, fcreg, prevOut);   // odd tail (phase 7 only)
}

// ---------------- PELT DP with precomputed costs: one wave/batch, phased by active
// slot count, INF-coded candidate set, v_min_f64 DPP wave reduce.
__global__ __launch_bounds__(64, 1) void k_pelt(const double* __restrict__ costM,
                                                int* __restrict__ prevG) {
    int b = blockIdx.x;
    int lane = threadIdx.x;
    const double* cm = costM + (size_t)b * 512 * 512;
    int* prevOut = prevG + b * 512;
    double fcreg[8];
    #pragma unroll
    for (int p = 0; p < 8; p++) fcreg[p] = INFINITY;
    if (lane == 0) fcreg[0] = -PEN;   // Fc[0]; candidate 0 present
    pelt_phase<0>(cm, lane, fcreg, prevOut);
    pelt_phase<1>(cm, lane, fcreg, prevOut);
    pelt_phase<2>(cm, lane, fcreg, prevOut);
    pelt_phase<3>(cm, lane, fcreg, prevOut);
    pelt_phase<4>(cm, lane, fcreg, prevOut);
    pelt_phase<5>(cm, lane, fcreg, prevOut);
    pelt_phase<6>(cm, lane, fcreg, prevOut);
    pelt_phase<7>(cm, lane, fcreg, prevOut);
}

// ---------------- fallback PELT (round-2 version) if workspace can't hold cost matrix
__global__ __launch_bounds__(64) void k_pelt_slow(const double* __restrict__ cs,
                                                  const double* __restrict__ cs2,
                                                  int* __restrict__ prevG) {
    __shared__ double sFc[512];
    __shared__ double sVal[512];
    __shared__ unsigned short sCand[512];
    int b = blockIdx.x;
    int lane = threadIdx.x;
    const double* c1 = cs + (size_t)b * 512 * NB;
    const double* c2 = cs2 + (size_t)b * 512 * NB;
    if (lane == 0) { sFc[0] = -PEN; sCand[0] = 0; }
    __syncthreads();
    int ncand = 1;
    for (int t = 1; t <= NF; t++) {
        const double* ct1 = c1 + (size_t)t * NB;
        const double* ct2 = c2 + (size_t)t * NB;
        int passes = (ncand + 63) >> 6;
        double bmv = INFINITY;
        int bmi = 0x7fffffff;
        for (int p = 0; p < passes; p++) {
            int slot = (p << 6) + lane;
            double val = INFINITY;
            if (slot < ncand) {
                int cc = sCand[slot];
                double nn = (double)(t - cc);
                const double* p1 = c1 + (size_t)cc * NB;
                const double* p2 = c2 + (size_t)cc * NB;
                double r[8];
                #pragma unroll
                for (int j = 0; j < 8; j++) {
                    double ss = ct1[j] - p1[j]; double s2 = ct2[j] - p2[j];
                    r[j] = s2 - ss * ss / nn;
                }
                #pragma unroll
                for (int base = 8; base < 32; base += 8)
                    #pragma unroll
                    for (int j = 0; j < 8; j++) {
                        int d = base + j;
                        double ss = ct1[d] - p1[d]; double s2 = ct2[d] - p2[d];
                        r[j] += s2 - ss * ss / nn;
                    }
                double res = ((r[0] + r[1]) + (r[2] + r[3])) + ((r[4] + r[5]) + (r[6] + r[7]));
                { double ss = ct1[32] - p1[32]; double s2 = ct2[32] - p2[32]; res += s2 - ss * ss / nn; }
                val = sFc[cc] + res + PEN;
                if (val < bmv) { bmv = val; bmi = slot; }
            }
            sVal[slot] = val;
        }
        #pragma unroll
        for (int off = 1; off < 64; off <<= 1) {
            double ov = __shfl_xor(bmv, off);
            int oi = __shfl_xor(bmi, off);
            if (ov < bmv || (ov == bmv && oi < bmi)) { bmv = ov; bmi = oi; }
        }
        double thr = bmv + PEN;
        if (lane == 0) {
            sFc[t] = bmv;
            prevG[b * 512 + t] = (int)sCand[bmi];
        }
        __syncthreads();
        int base = 0;
        for (int p = 0; p < passes; p++) {
            int slot = (p << 6) + lane;
            int cc = (slot < ncand) ? (int)sCand[slot] : 0;
            bool keep = (slot < ncand) && (sVal[slot] <= thr);
            unsigned long long mask = __ballot(keep);
            if (keep) sCand[base + __popcll(mask & ((1ull << lane) - 1ull))] = (unsigned short)cc;
            base += (int)__popcll(mask);
        }
        if (lane == 0) sCand[base] = (unsigned short)t;
        ncand = base + 1;
        __syncthreads();
    }
}

// ---------------- backtrack + bounds + segment table + bin offsets (1 thread per batch)
__global__ void k_bounds(const int* __restrict__ prevG, int* __restrict__ bps, int* __restrict__ bnds,
                         int* __restrict__ segS, int* __restrict__ segE, int* __restrict__ nsegA,
                         int* __restrict__ binoff) {
    int b = threadIdx.x;
    if (b >= Bn) return;
    const int* pv = prevG + b * 512;
    int* bp = bps + b * 512;
    int* bd = bnds + b * 520;
    int cnt = 0, t = NF;
    while (t > 0) { bp[cnt++] = t; t = pv[t]; }
    int nb = 1; bd[0] = 0;
    for (int i = cnt - 1; i >= 1; --i) {
        int k = bp[i];
        int bb = 32 * k;
        if (bb > Ln) bb = Ln;
        if (bb - bd[nb - 1] >= 8) bd[nb++] = bb;
    }
    if (Ln - bd[nb - 1] < 8 && nb > 1) nb--;
    bd[nb++] = Ln;
    int ns = nb - 1;
    nsegA[b] = ns;
    int off = 0;
    for (int j = 0; j < ns; j++) {
        int s = bd[j], e = bd[j + 1];
        segS[b * 512 + j] = s; segE[b * 512 + j] = e;
        binoff[b * 513 + j] = off;
        off += (e - s) >> 1;
    }
    binoff[b * 513 + ns] = off;
}

// ---------------- per-segment mean (double)
__global__ void k_segmean(const float* __restrict__ sig, const int* __restrict__ segS,
                          const int* __restrict__ segE, const int* __restrict__ nsegA,
                          double* __restrict__ segMean) {
    __shared__ double red[256];
    int b = blockIdx.y, j = blockIdx.x;
    if (j >= nsegA[b]) return;
    int s = segS[b * 512 + j], e = segE[b * 512 + j];
    double acc = 0.0;
    for (int i = s + threadIdx.x; i < e; i += 256) acc += (double)sig[b * Ln + i];
    red[threadIdx.x] = acc;
    __syncthreads();
    for (int st = 128; st >= 1; st >>= 1) {
        if (threadIdx.x < st) red[threadIdx.x] += red[threadIdx.x + st];
        __syncthreads();
    }
    if (threadIdx.x == 0) segMean[b * 512 + j] = red[0] / (double)(e - s);
}

// ---------------- segment DFT: one wave per (batch, bin-slot), rotation recurrence in double
__global__ __launch_bounds__(256) void k_spec(const float* __restrict__ sig,
                                              const double* __restrict__ segMean,
                                              const int* __restrict__ segS, const int* __restrict__ segE,
                                              const int* __restrict__ nsegA, const int* __restrict__ binoff,
                                              double* __restrict__ spec) {
    int b = blockIdx.y;
    int wv = threadIdx.x >> 6, lane = threadIdx.x & 63;
    int slot = blockIdx.x * 4 + wv;
    int ns = nsegA[b];
    const int* off = binoff + b * 513;
    if (slot >= off[ns]) return;
    int lo = 0, hi = ns - 1;
    while (lo < hi) { int mid = (lo + hi + 1) >> 1; if (off[mid] <= slot) lo = mid; else hi = mid - 1; }
    int j = lo;
    int s = segS[b * 512 + j], e = segE[b * 512 + j], n = e - s;
    int k = slot - off[j] + 1;
    float m32 = (float)segMean[b * 512 + j];
    long j0 = ((long)lane * (long)k) % (long)n;
    long js = (64L * (long)k) % (long)n;
    double a0 = (2.0 * M_PI * (double)j0) / (double)n;
    double as = (2.0 * M_PI * (double)js) / (double)n;
    double cr, sr, cb, sb;
    sincos(a0, &sr, &cr);
    sincos(as, &sb, &cb);
    double re = 0.0, im = 0.0;
    const float* sp = sig + b * Ln + s;
    for (int tt = lane; tt < n; tt += 64) {
        double v = (double)(sp[tt] - m32);
        re += v * cr;
        im += v * sr;
        double nc = cr * cb - sr * sb;
        sr = sr * cb + cr * sb;
        cr = nc;
    }
    #pragma unroll
    for (int o = 32; o >= 1; o >>= 1) { re += __shfl_down(re, o); im += __shfl_down(im, o); }
    if (lane == 0) spec[(size_t)b * TB + slot] = re * re + im * im;
}

// ---------------- per-segment stats
__global__ void k_stats(const double* __restrict__ spec, const int* __restrict__ segS,
                        const int* __restrict__ segE, const int* __restrict__ nsegA,
                        const int* __restrict__ binoff, int* __restrict__ segPL,
                        double* __restrict__ segDP, double* __restrict__ segBW,
                        int* __restrict__ segNT) {
    __shared__ double rv[256]; __shared__ int ri[256];
    __shared__ double rt[256], rs[256];
    __shared__ double sC, sTot;
    int b = blockIdx.y, j = blockIdx.x;
    if (j >= nsegA[b]) return;
    int s = segS[b * 512 + j], e = segE[b * 512 + j], n = e - s, nf = n >> 1;
    const double* base = spec + (size_t)b * TB + binoff[b * 513 + j];
    int tid = threadIdx.x;
    double mv = -INFINITY; int mi = 0x7fffffff; double tot = 0.0, s1 = 0.0;
    for (int i = tid; i < nf; i += 256) {
        double vv = base[i];
        double f = (double)(i + 1) / (double)nf;
        tot += vv; s1 += vv * f;
        if (vv > mv) { mv = vv; mi = i; }
    }
    rv[tid] = mv; ri[tid] = mi; rt[tid] = tot; rs[tid] = s1;
    __syncthreads();
    for (int st = 128; st >= 1; st >>= 1) {
        if (tid < st) {
            double ov = rv[tid + st]; int oi = ri[tid + st];
            if (ov > rv[tid] || (ov == rv[tid] && oi < ri[tid])) { rv[tid] = ov; ri[tid] = oi; }
            rt[tid] += rt[tid + st]; rs[tid] += rs[tid + st];
        }
        __syncthreads();
    }
    if (tid == 0) { sTot = rt[0]; sC = rs[0] / rt[0]; }
    __syncthreads();
    double c = sC, totv = sTot;
    double s2 = 0.0;
    for (int i = tid; i < nf; i += 256) {
        double f = (double)(i + 1) / (double)nf;
        double d = f - c;
        s2 += base[i] * d * d;
    }
    rt[tid] = s2;
    __syncthreads();
    for (int st = 128; st >= 1; st >>= 1) {
        if (tid < st) rt[tid] += rt[tid + st];
        __syncthreads();
    }
    if (tid == 0) {
        double dp, bw;
        if (n < 4) { dp = (double)(n > 0 ? n : 1); bw = 0.0; }
        else if (!(totv > 0.0)) { dp = (double)n; bw = 0.0; }
        else { int kk = ri[0] + 1; dp = (double)n / (double)kk; bw = sqrt(rt[0] / totv); }
        double raw = 1.0 * dp / (1.0 + 1.0 * bw);
        double rr = rint(raw / 2.0);          // Python round(): half-to-even
        long pl = 2L * (long)rr;
        if (pl < 8) pl = 8;
        if (pl > 64) pl = 64;
        int nfull = n / (int)pl;
        int ntok = nfull + ((nfull * (int)pl < n) ? 1 : 0);
        segPL[b * 512 + j] = (int)pl; segDP[b * 512 + j] = dp;
        segBW[b * 512 + j] = bw; segNT[b * 512 + j] = ntok;
    }
}

// ---------------- token prefix offsets per batch
__global__ void k_tokpref(const int* __restrict__ nsegA, const int* __restrict__ segNT,
                          int* __restrict__ tokoff, int* __restrict__ ntokA) {
    int b = threadIdx.x;
    if (b >= Bn) return;
    int ns = nsegA[b]; int off = 0;
    for (int j = 0; j < ns; j++) { tokoff[b * 513 + j] = off; off += segNT[b * 512 + j]; }
    tokoff[b * 513 + ns] = off;
    ntokA[b] = off;
}

// ---------------- fill all outputs: one block per (batch, token)
__global__ __launch_bounds__(256) void k_fill(const float* __restrict__ x,
                                              const int* __restrict__ segS, const int* __restrict__ segE,
                                              const int* __restrict__ segPL, const double* __restrict__ segDP,
                                              const double* __restrict__ segBW, const int* __restrict__ nsegA,
                                              const int* __restrict__ tokoff, const int* __restrict__ ntokA,
                                              float* __restrict__ out, int MT) {
    int b = blockIdx.y, tok = blockIdx.x;
    int nt = ntokA[b];
    if (tok >= nt) return;
    int ns = nsegA[b];
    const int* toff = tokoff + b * 513;
    int lo = 0, hi = ns - 1;
    while (lo < hi) { int mid = (lo + hi + 1) >> 1; if (toff[mid] <= tok) lo = mid; else hi = mid - 1; }
    int j = lo;
    int s = segS[b * 512 + j], e = segE[b * 512 + j], pl = segPL[b * 512 + j];
    int idx = tok - toff[j];
    int nfull = (e - s) / pl;
    int st, en;
    if (idx < nfull) { st = s + idx * pl; en = st + pl; }
    else { st = s + nfull * pl; en = e; }
    int ilen = en - st;
    float scale = (float)ilen / 16.0f;
    int tid = threadIdx.x;
    size_t pbase = ((size_t)(b * MT + tok)) * (Cn * 16);
    const float* xb = x + (size_t)b * Cn * Ln;
    #pragma unroll
    for (int r = 0; r < 2; r++) {
        int eidx = tid + r * 256;
        int c = eidx >> 4, jo = eidx & 15;
        float coords = ((float)jo + 0.5f) * scale - 0.5f;
        if (coords < 0.0f) coords = 0.0f;
        float mx = (float)(ilen - 1);
        if (coords > mx) coords = mx;
        int l2 = (int)floorf(coords);
        int h2 = l2 + 1;
        if (h2 > ilen - 1) h2 = ilen - 1;
        float w = coords - (float)l2;
        const float* xc = xb + (size_t)c * Ln + st;
        out[pbase + eidx] = xc[l2] * (1.0f - w) + xc[h2] * w;
    }
    if (tid == 0) {
        size_t BT = (size_t)Bn * MT;
        size_t o_mask = BT * 512;
        size_t pos = (size_t)b * MT + tok;
        out[o_mask + pos] = 1.0f;                                  // mask
        out[o_mask + BT + pos] = (float)st;                        // start
        out[o_mask + 2 * BT + pos] = (float)en;                    // end
        out[o_mask + 3 * BT + pos] = (((float)st + (float)en) - 1.0f) * 0.5f / 16383.0f;  // center
        out[o_mask + 4 * BT + pos] = (float)(en - st) / 16384.0f;  // span
        double dp = segDP[b * 512 + j], bwv = segBW[b * 512 + j];
        size_t o_rg = o_mask + 5 * BT;
        out[o_rg + pos * 3 + 0] = (float)(dp / 16384.0);
        out[o_rg + pos * 3 + 1] = (float)bwv;
        out[o_rg + pos * 3 + 2] = (float)((double)(e - s) / 16384.0);
        if (tok == 0) out[o_mask + 8 * BT + b] = (float)nt;        // n_tok
    }
}

extern "C" void kernel_launch(void* const* d_in, const int* in_sizes, int n_in,
                              void* d_out, int out_size, void* d_ws, size_t ws_size,
                              hipStream_t stream) {
    (void)in_sizes; (void)n_in;
    const float* x = (const float*)d_in[0];
    float* out = (float*)d_out;
    char* ws = (char*)d_ws;
    size_t o = 0;
    auto alloc = [&](size_t bytes) -> char* {
        char* r = ws + o;
        o = (o + bytes + 511) & ~(size_t)511;
        return r;
    };
    float* sig = (float*)alloc((size_t)Bn * Ln * 4);
    float* fm = (float*)alloc((size_t)Bn * NF * 4);
    double* feats = (double*)alloc((size_t)Bn * NF * NB * 8);
    double* cs = (double*)alloc((size_t)Bn * 512 * NB * 8);
    double* cs2 = (double*)alloc((size_t)Bn * 512 * NB * 8);
    int* prevG = (int*)alloc((size_t)Bn * 512 * 4);
    int* bps = (int*)alloc((size_t)Bn * 512 * 4);
    int* bnds = (int*)alloc((size_t)Bn * 520 * 4);
    int* nsegA = (int*)alloc((size_t)Bn * 4);
    int* segS = (int*)alloc((size_t)Bn * 512 * 4);
    int* segE = (int*)alloc((size_t)Bn * 512 * 4);
    int* segPL = (int*)alloc((size_t)Bn * 512 * 4);
    int* segNT = (int*)alloc((size_t)Bn * 512 * 4);
    double* segDP = (double*)alloc((size_t)Bn * 512 * 8);
    double* segBW = (double*)alloc((size_t)Bn * 512 * 8);
    double* segMean = (double*)alloc((size_t)Bn * 512 * 8);
    int* binoff = (int*)alloc((size_t)Bn * 513 * 4);
    int* tokoff = (int*)alloc((size_t)Bn * 513 * 4);
    int* ntokA = (int*)alloc((size_t)Bn * 4);
    double* spec = (double*)alloc((size_t)Bn * TB * 8);
    size_t costBytes = (size_t)Bn * 512 * 512 * 8;   // 67 MB
    double* costM = (double*)alloc(costBytes);
    bool haveCost = (o <= ws_size);

    int MT = (out_size / Bn - 1) / 520;   // out_size = Bn*(MT*520 + 1)

    hipMemsetAsync(d_out, 0, (size_t)out_size * 4, stream);
    k_sig<<<(Bn * Ln + 255) / 256, 256, 0, stream>>>(x, sig);
    k_fmean<<<(Bn * NF + 255) / 256, 256, 0, stream>>>(sig, fm);
    k_feats<<<Bn * NF, 64, 0, stream>>>(sig, fm, feats);
    k_cumsum<<<(Bn * NB + 255) / 256, 256, 0, stream>>>(feats, cs, cs2);
    if (haveCost) {
        k_cost<<<dim3(NF, Bn), 256, 0, stream>>>(cs, cs2, costM);
        k_pelt<<<Bn, 64, 0, stream>>>(costM, prevG);
    } else {
        k_pelt_slow<<<Bn, 64, 0, stream>>>(cs, cs2, prevG);
    }
    k_bounds<<<1, 32, 0, stream>>>(prevG, bps, bnds, segS, segE, nsegA, binoff);
    k_segmean<<<dim3(MAXSEG, Bn), 256, 0, stream>>>(sig, segS, segE, nsegA, segMean);
    k_spec<<<dim3(TB / 4, Bn), 256, 0, stream>>>(sig, segMean, segS, segE, nsegA, binoff, spec);
    k_stats<<<dim3(MAXSEG, Bn), 256, 0, stream>>>(spec, segS, segE, nsegA, binoff,
                                                  segPL, segDP, segBW, segNT);
    k_tokpref<<<1, 32, 0, stream>>>(nsegA, segNT, tokoff, ntokA);
    if (MT > 0)
        k_fill<<<dim3(MT, Bn), 256, 0, stream>>>(x, segS, segE, segPL, segDP, segBW,
                                                 nsegA, tokoff, ntokA, out, MT);
}

// Round 5
// 1061.053 us; speedup vs baseline: 1.5567x; 1.2358x over previous
//
#include <hip/hip_runtime.h>
#include <math.h>

#define Bn 32
#define Cn 32
#define Ln 16384
#define NF 511      // number of spectrogram frames
#define NB 33       // rfft bins of 64-pt window
#define MAXSEG 512
#define TB 8192     // total spectral bins per batch (sum of nf over segments = L/2)
#define PEN 5.0

// ---------------- sig = x.mean(axis=channels), float32 sequential (numpy axis-0 reduce order)
__global__ void k_sig(const float* __restrict__ x, float* __restrict__ sig) {
    int idx = blockIdx.x * 256 + threadIdx.x;
    if (idx >= Bn * Ln) return;
    int b = idx >> 14;
    int t = idx & (Ln - 1);
    const float* p = x + ((size_t)b * Cn) * Ln + t;
    float a = p[0];
    #pragma unroll
    for (int c = 1; c < Cn; c++) a += p[(size_t)c * Ln];
    sig[idx] = a / 32.0f;
}

// ---------------- frame means: numpy scalar pairwise 8-accumulator pattern, n=64, float32
__global__ void k_fmean(const float* __restrict__ sig, float* __restrict__ fm) {
    int idx = blockIdx.x * 256 + threadIdx.x;
    if (idx >= Bn * NF) return;
    int b = idx / NF, f = idx - b * NF;
    const float* a = sig + b * Ln + f * 32;
    float r[8];
    #pragma unroll
    for (int j = 0; j < 8; j++) r[j] = a[j];
    #pragma unroll
    for (int base = 8; base < 64; base += 8)
        #pragma unroll
        for (int j = 0; j < 8; j++) r[j] += a[base + j];
    float res = ((r[0] + r[1]) + (r[2] + r[3])) + ((r[4] + r[5]) + (r[6] + r[7]));
    fm[idx] = res / 64.0f;
}

// ---------------- feats = log(|rfft(hann * (frame - mean))|^2 + 1e-8), double
__global__ void k_feats(const float* __restrict__ sig, const float* __restrict__ fm,
                        double* __restrict__ feats) {
    __shared__ double v[64], ct[64], stb[64];
    int bf = blockIdx.x;
    int b = bf / NF, f = bf - b * NF;
    int i = threadIdx.x;  // 0..63
    double ang = (2.0 * M_PI * (double)i) / 64.0;
    double sn, cx;
    sincos(ang, &sn, &cx);
    ct[i] = cx; stb[i] = sn;
    int n2 = 2 * i - 63;                       // np.hanning: arange(1-M, M, 2)
    double w = 0.5 + 0.5 * cos((M_PI * (double)n2) / 63.0);
    float m = fm[bf];
    v[i] = (double)(sig[b * Ln + f * 32 + i] - m) * w;   // f32 subtract, f64 window mult
    __syncthreads();
    if (i < NB) {
        double re = 0.0, im = 0.0;
        for (int t = 0; t < 64; t++) {
            int j = (t * i) & 63;
            re += v[t] * ct[j];
            im += v[t] * stb[j];
        }
        double spec = re * re + im * im;
        feats[(size_t)bf * NB + i] = log(spec + 1e-8);
    }
}

// ---------------- cs / cs2 cumsums (sequential double, numpy cumsum order)
__global__ void k_cumsum(const double* __restrict__ feats, double* __restrict__ cs,
                         double* __restrict__ cs2) {
    int idx = blockIdx.x * 256 + threadIdx.x;
    if (idx >= Bn * NB) return;
    int b = idx / NB, d = idx - b * NB;
    const double* fp = feats + (size_t)b * NF * NB + d;
    double* c1 = cs + (size_t)b * 512 * NB + d;
    double* c2 = cs2 + (size_t)b * 512 * NB + d;
    double a1 = 0.0, a2 = 0.0;
    c1[0] = 0.0; c2[0] = 0.0;
    for (int t = 0; t < NF; t++) {
        double vv = fp[(size_t)t * NB];
        a1 += vv;
        a2 += vv * vv;
        c1[(size_t)(t + 1) * NB] = a1;
        c2[(size_t)(t + 1) * NB] = a2;
    }
}

// ---------------- precompute cost(c,t) for all pairs, massively parallel, exact numpy op order
__global__ __launch_bounds__(256) void k_cost(const double* __restrict__ cs,
                                              const double* __restrict__ cs2,
                                              double* __restrict__ costM) {
    int t = blockIdx.x + 1;   // 1..NF
    int b = blockIdx.y;
    const double* c1 = cs + (size_t)b * 512 * NB;
    const double* c2 = cs2 + (size_t)b * 512 * NB;
    __shared__ double sct1[NB], sct2[NB];
    if (threadIdx.x < NB) {
        sct1[threadIdx.x] = c1[(size_t)t * NB + threadIdx.x];
        sct2[threadIdx.x] = c2[(size_t)t * NB + threadIdx.x];
    }
    __syncthreads();
    double* outp = costM + ((size_t)b * 512 + (size_t)t) * 512;
    for (int c = threadIdx.x; c < t; c += 256) {
        double nn = (double)(t - c);
        const double* p1 = c1 + (size_t)c * NB;
        const double* p2 = c2 + (size_t)c * NB;
        // numpy pairwise sum over 33 dims: 8 accumulators + remainder
        double r[8];
        #pragma unroll
        for (int j = 0; j < 8; j++) {
            double ss = sct1[j] - p1[j]; double s2 = sct2[j] - p2[j];
            r[j] = s2 - ss * ss / nn;
        }
        #pragma unroll
        for (int base = 8; base < 32; base += 8)
            #pragma unroll
            for (int j = 0; j < 8; j++) {
                int d = base + j;
                double ss = sct1[d] - p1[d]; double s2 = sct2[d] - p2[d];
                r[j] += s2 - ss * ss / nn;
            }
        double res = ((r[0] + r[1]) + (r[2] + r[3])) + ((r[4] + r[5]) + (r[6] + r[7]));
        { double ss = sct1[32] - p1[32]; double s2 = sct2[32] - p2[32]; res += s2 - ss * ss / nn; }
        outp[c] = res;
    }
}

// ---------------- f64 helpers: DPP move and wave-64 min on the VALU pipe (v_min_f64).
// update_dpp with bound_ctrl=false and old=self: invalid-source lanes keep their own
// value, the identity for min.
template <int CTRL>
__device__ __forceinline__ double dpp_mov_f64(double v) {
    int lo = __double2loint(v), hi = __double2hiint(v);
    int slo = __builtin_amdgcn_update_dpp(lo, lo, CTRL, 0xF, 0xF, false);
    int shi = __builtin_amdgcn_update_dpp(hi, hi, CTRL, 0xF, 0xF, false);
    return __hiloint2double(shi, slo);
}
__device__ __forceinline__ double rl_f64(double v, int l) {
    int lo = __builtin_amdgcn_readlane(__double2loint(v), l);
    int hi = __builtin_amdgcn_readlane(__double2hiint(v), l);
    return __hiloint2double(hi, lo);
}
// 4 row_shr stages put each 16-lane row's min in lanes 15/31/47/63; combine via
// readlane (chain: 4 dpp-min stages + 2-level min tree), result wave-uniform.
__device__ __forceinline__ double wave_min_f64(double v) {
    v = fmin(v, dpp_mov_f64<0x111>(v));   // row_shr:1
    v = fmin(v, dpp_mov_f64<0x112>(v));   // row_shr:2
    v = fmin(v, dpp_mov_f64<0x114>(v));   // row_shr:4
    v = fmin(v, dpp_mov_f64<0x118>(v));   // row_shr:8
    double a = rl_f64(v, 15), b = rl_f64(v, 31);
    double c = rl_f64(v, 47), d = rl_f64(v, 63);
    return fmin(fmin(a, b), fmin(c, d));
}

// ---------------- one PELT DP step over NP active slots.
// Candidate representation: fcreg[p] (lane-owned Fc[p*64+lane]) is +INF for
// absent/pruned candidates -- no mask needed: INF + cost + PEN = INF, which loses
// every fmin and fails the ==bmin ballot. Garbage cost rows (c >= t, uninitialized)
// sit behind INF fcreg; a NaN produced by INF+garbage is ignored by
// v_min_f64 (minNum) and compares false in the ballot.
template <int NP>
__device__ __forceinline__ void pelt_step(int t, int lane, const double (&cur)[8],
                                          double (&fcreg)[8], int* __restrict__ prevOut) {
    double vals[NP];
    #pragma unroll
    for (int p = 0; p < NP; p++) vals[p] = fcreg[p] + cur[p] + PEN;   // (Fc+cost)+PEN, numpy order
    // balanced local min tree over NP slots
    double red[NP];
    #pragma unroll
    for (int p = 0; p < NP; p++) red[p] = vals[p];
    #pragma unroll
    for (int s = 1; s < NP; s <<= 1)
        #pragma unroll
        for (int p = 0; p + s < NP; p += 2 * s) red[p] = fmin(red[p], red[p + s]);
    double bmin = wave_min_f64(red[0]);
    // first-occurrence argmin: smallest c with vals == bmin (c = (p<<6)+lane).
    // Descending-p overwrite + lowest set lane bit = smallest c; wave-uniform.
    int bc = 0;
    #pragma unroll
    for (int p = NP - 1; p >= 0; p--) {
        unsigned long long m = __ballot(vals[p] == bmin);
        if (m != 0ull) bc = (p << 6) + (__ffsll(m) - 1);
    }
    if (lane == 0) prevOut[t] = bc;
    // prune: candidates with val > Fc[t]+PEN become +INF (absent lanes stay INF)
    double thr = bmin + PEN;
    #pragma unroll
    for (int p = 0; p < NP; p++)
        if (!(vals[p] <= thr)) fcreg[p] = INFINITY;
    // add candidate t: latch Fc[t]=bmin into its owning lane. Within phase K,
    // t>>6 is K except at the boundary step t=64(K+1) where it is K+1.
    #pragma unroll
    for (int p = NP - 1; p <= NP; p++)
        if (p < 8 && p == (t >> 6) && lane == (t & 63)) fcreg[p] = bmin;
}

// ---------------- one phase: t in [64K+1, min(64K+64, NF)], NP=K+1 active slots.
// Depth-2 register double-buffer (4 bufs x NP doubles <= 64 VGPRs even at NP=8, so
// the allocator can actually keep the pipeline).
template <int K>
__device__ __forceinline__ void pelt_phase(const double* __restrict__ cm, int lane,
                                           double (&fcreg)[8], int* __restrict__ prevOut) {
    constexpr int NP = K + 1;
    const int t0 = 64 * K + 1;
    const int t1 = (64 * K + 64 < NF) ? (64 * K + 64) : NF;   // inclusive
    double r0[8], r1[8], n0[8], n1[8];
    #pragma unroll
    for (int p = 0; p < NP; p++) {
        r0[p] = cm[(size_t)t0 * 512 + (p << 6) + lane];
        r1[p] = cm[(size_t)(t0 + 1) * 512 + (p << 6) + lane];   // t0+1 <= 450 <= NF always
    }
    int t = t0;
    for (; t + 1 <= t1; t += 2) {
        int q0 = t + 2, q1 = t + 3;
        if (q0 > NF) q0 = NF;
        if (q1 > NF) q1 = NF;
        #pragma unroll
        for (int p = 0; p < NP; p++) {
            n0[p] = cm[(size_t)q0 * 512 + (p << 6) + lane];
            n1[p] = cm[(size_t)q1 * 512 + (p << 6) + lane];
        }
        pelt_step<NP>(t, lane, r0, fcreg, prevOut);
        pelt_step<NP>(t + 1, lane, r1, fcreg, prevOut);
        #pragma unroll
        for (int p = 0; p < NP; p++) { r0[p] = n0[p]; r1[p] = n1[p]; }
    }
    if (t <= t1) pelt_step<NP>(t, lane, r0, fcreg, prevOut);   // odd tail (phase 7 only)
}

// ---------------- PELT DP with precomputed costs: one wave/batch, phased by active
// slot count, INF-coded candidate set, v_min_f64 DPP wave reduce.
__global__ __launch_bounds__(64, 1) void k_pelt(const double* __restrict__ costM,
                                                int* __restrict__ prevG) {
    int b = blockIdx.x;
    int lane = threadIdx.x;
    const double* cm = costM + (size_t)b * 512 * 512;
    int* prevOut = prevG + b * 512;
    double fcreg[8];
    #pragma unroll
    for (int p = 0; p < 8; p++) fcreg[p] = INFINITY;
    if (lane == 0) fcreg[0] = -PEN;   // Fc[0]; candidate 0 present
    pelt_phase<0>(cm, lane, fcreg, prevOut);
    pelt_phase<1>(cm, lane, fcreg, prevOut);
    pelt_phase<2>(cm, lane, fcreg, prevOut);
    pelt_phase<3>(cm, lane, fcreg, prevOut);
    pelt_phase<4>(cm, lane, fcreg, prevOut);
    pelt_phase<5>(cm, lane, fcreg, prevOut);
    pelt_phase<6>(cm, lane, fcreg, prevOut);
    pelt_phase<7>(cm, lane, fcreg, prevOut);
}

// ---------------- fallback PELT (round-2 version) if workspace can't hold cost matrix
__global__ __launch_bounds__(64) void k_pelt_slow(const double* __restrict__ cs,
                                                  const double* __restrict__ cs2,
                                                  int* __restrict__ prevG) {
    __shared__ double sFc[512];
    __shared__ double sVal[512];
    __shared__ unsigned short sCand[512];
    int b = blockIdx.x;
    int lane = threadIdx.x;
    const double* c1 = cs + (size_t)b * 512 * NB;
    const double* c2 = cs2 + (size_t)b * 512 * NB;
    if (lane == 0) { sFc[0] = -PEN; sCand[0] = 0; }
    __syncthreads();
    int ncand = 1;
    for (int t = 1; t <= NF; t++) {
        const double* ct1 = c1 + (size_t)t * NB;
        const double* ct2 = c2 + (size_t)t * NB;
        int passes = (ncand + 63) >> 6;
        double bmv = INFINITY;
        int bmi = 0x7fffffff;
        for (int p = 0; p < passes; p++) {
            int slot = (p << 6) + lane;
            double val = INFINITY;
            if (slot < ncand) {
                int cc = sCand[slot];
                double nn = (double)(t - cc);
                const double* p1 = c1 + (size_t)cc * NB;
                const double* p2 = c2 + (size_t)cc * NB;
                double r[8];
                #pragma unroll
                for (int j = 0; j < 8; j++) {
                    double ss = ct1[j] - p1[j]; double s2 = ct2[j] - p2[j];
                    r[j] = s2 - ss * ss / nn;
                }
                #pragma unroll
                for (int base = 8; base < 32; base += 8)
                    #pragma unroll
                    for (int j = 0; j < 8; j++) {
                        int d = base + j;
                        double ss = ct1[d] - p1[d]; double s2 = ct2[d] - p2[d];
                        r[j] += s2 - ss * ss / nn;
                    }
                double res = ((r[0] + r[1]) + (r[2] + r[3])) + ((r[4] + r[5]) + (r[6] + r[7]));
                { double ss = ct1[32] - p1[32]; double s2 = ct2[32] - p2[32]; res += s2 - ss * ss / nn; }
                val = sFc[cc] + res + PEN;
                if (val < bmv) { bmv = val; bmi = slot; }
            }
            sVal[slot] = val;
        }
        #pragma unroll
        for (int off = 1; off < 64; off <<= 1) {
            double ov = __shfl_xor(bmv, off);
            int oi = __shfl_xor(bmi, off);
            if (ov < bmv || (ov == bmv && oi < bmi)) { bmv = ov; bmi = oi; }
        }
        double thr = bmv + PEN;
        if (lane == 0) {
            sFc[t] = bmv;
            prevG[b * 512 + t] = (int)sCand[bmi];
        }
        __syncthreads();
        int base = 0;
        for (int p = 0; p < passes; p++) {
            int slot = (p << 6) + lane;
            int cc = (slot < ncand) ? (int)sCand[slot] : 0;
            bool keep = (slot < ncand) && (sVal[slot] <= thr);
            unsigned long long mask = __ballot(keep);
            if (keep) sCand[base + __popcll(mask & ((1ull << lane) - 1ull))] = (unsigned short)cc;
            base += (int)__popcll(mask);
        }
        if (lane == 0) sCand[base] = (unsigned short)t;
        ncand = base + 1;
        __syncthreads();
    }
}

// ---------------- backtrack + bounds + segment table + bin offsets.
// One block per batch. prevG (2 KB) is staged into LDS with 64 coalesced lanes,
// so the inherently-serial backtrack chain t=prev[t] pays ~120 cy/hop LDS latency
// instead of ~600-900 cy global latency (this kernel was 315 us as a single
// 32-thread block walking the chain through global memory -- pure latency, 0.4 MB
// traffic). Serial bounds logic keeps running values in registers; output writes
// are parallelized. Since every bound is a multiple of 32 (bb=32k, Ln=16384),
// segment lengths are even and binoff[j] == bd[j]/2 exactly.
__global__ __launch_bounds__(64) void k_bounds(const int* __restrict__ prevG,
                                               int* __restrict__ segS, int* __restrict__ segE,
                                               int* __restrict__ nsegA, int* __restrict__ binoff) {
    __shared__ int sPrev[512];
    __shared__ int sBp[512];
    __shared__ int sBd[520];
    __shared__ int sNs;
    int b = blockIdx.x;
    int tid = threadIdx.x;
    const int* pv = prevG + b * 512;
    #pragma unroll
    for (int i = 0; i < 8; i++) sPrev[tid + i * 64] = pv[tid + i * 64];
    __syncthreads();
    if (tid == 0) {
        // backtrack (dependent LDS chain, <=511 hops)
        int cnt = 0, t = NF;
        while (t > 0) { sBp[cnt++] = t; t = sPrev[t]; }
        // bounds ascending over bps[:-1] (= sBp[cnt-1..1]); last bound in register
        int nbv = 1; sBd[0] = 0; int last = 0;
        for (int i = cnt - 1; i >= 1; --i) {
            int k = sBp[i];
            int bb = 32 * k;
            if (bb > Ln) bb = Ln;
            if (bb - last >= 8) { sBd[nbv++] = bb; last = bb; }
        }
        if (Ln - last < 8 && nbv > 1) nbv--;
        sBd[nbv++] = Ln;
        int ns = nbv - 1;
        nsegA[b] = ns;
        sNs = ns;
    }
    __syncthreads();
    int ns = sNs;
    for (int j = tid; j < ns; j += 64) {
        int s = sBd[j], e = sBd[j + 1];
        segS[b * 512 + j] = s;
        segE[b * 512 + j] = e;
        binoff[b * 513 + j] = s >> 1;        // prefix of (e-s)/2 with all lengths even
    }
    if (tid == 0) binoff[b * 513 + ns] = sBd[ns] >> 1;
}

// ---------------- per-segment mean (double)
__global__ void k_segmean(const float* __restrict__ sig, const int* __restrict__ segS,
                          const int* __restrict__ segE, const int* __restrict__ nsegA,
                          double* __restrict__ segMean) {
    __shared__ double red[256];
    int b = blockIdx.y, j = blockIdx.x;
    if (j >= nsegA[b]) return;
    int s = segS[b * 512 + j], e = segE[b * 512 + j];
    double acc = 0.0;
    for (int i = s + threadIdx.x; i < e; i += 256) acc += (double)sig[b * Ln + i];
    red[threadIdx.x] = acc;
    __syncthreads();
    for (int st = 128; st >= 1; st >>= 1) {
        if (threadIdx.x < st) red[threadIdx.x] += red[threadIdx.x + st];
        __syncthreads();
    }
    if (threadIdx.x == 0) segMean[b * 512 + j] = red[0] / (double)(e - s);
}

// ---------------- segment DFT: one wave per (batch, bin-slot), rotation recurrence in double
__global__ __launch_bounds__(256) void k_spec(const float* __restrict__ sig,
                                              const double* __restrict__ segMean,
                                              const int* __restrict__ segS, const int* __restrict__ segE,
                                              const int* __restrict__ nsegA, const int* __restrict__ binoff,
                                              double* __restrict__ spec) {
    int b = blockIdx.y;
    int wv = threadIdx.x >> 6, lane = threadIdx.x & 63;
    int slot = blockIdx.x * 4 + wv;
    int ns = nsegA[b];
    const int* off = binoff + b * 513;
    if (slot >= off[ns]) return;
    int lo = 0, hi = ns - 1;
    while (lo < hi) { int mid = (lo + hi + 1) >> 1; if (off[mid] <= slot) lo = mid; else hi = mid - 1; }
    int j = lo;
    int s = segS[b * 512 + j], e = segE[b * 512 + j], n = e - s;
    int k = slot - off[j] + 1;
    float m32 = (float)segMean[b * 512 + j];
    long j0 = ((long)lane * (long)k) % (long)n;
    long js = (64L * (long)k) % (long)n;
    double a0 = (2.0 * M_PI * (double)j0) / (double)n;
    double as = (2.0 * M_PI * (double)js) / (double)n;
    double cr, sr, cb, sb;
    sincos(a0, &sr, &cr);
    sincos(as, &sb, &cb);
    double re = 0.0, im = 0.0;
    const float* sp = sig + b * Ln + s;
    for (int tt = lane; tt < n; tt += 64) {
        double v = (double)(sp[tt] - m32);
        re += v * cr;
        im += v * sr;
        double nc = cr * cb - sr * sb;
        sr = sr * cb + cr * sb;
        cr = nc;
    }
    #pragma unroll
    for (int o = 32; o >= 1; o >>= 1) { re += __shfl_down(re, o); im += __shfl_down(im, o); }
    if (lane == 0) spec[(size_t)b * TB + slot] = re * re + im * im;
}

// ---------------- per-segment stats
__global__ void k_stats(const double* __restrict__ spec, const int* __restrict__ segS,
                        const int* __restrict__ segE, const int* __restrict__ nsegA,
                        const int* __restrict__ binoff, int* __restrict__ segPL,
                        double* __restrict__ segDP, double* __restrict__ segBW,
                        int* __restrict__ segNT) {
    __shared__ double rv[256]; __shared__ int ri[256];
    __shared__ double rt[256], rs[256];
    __shared__ double sC, sTot;
    int b = blockIdx.y, j = blockIdx.x;
    if (j >= nsegA[b]) return;
    int s = segS[b * 512 + j], e = segE[b * 512 + j], n = e - s, nf = n >> 1;
    const double* base = spec + (size_t)b * TB + binoff[b * 513 + j];
    int tid = threadIdx.x;
    double mv = -INFINITY; int mi = 0x7fffffff; double tot = 0.0, s1 = 0.0;
    for (int i = tid; i < nf; i += 256) {
        double vv = base[i];
        double f = (double)(i + 1) / (double)nf;
        tot += vv; s1 += vv * f;
        if (vv > mv) { mv = vv; mi = i; }
    }
    rv[tid] = mv; ri[tid] = mi; rt[tid] = tot; rs[tid] = s1;
    __syncthreads();
    for (int st = 128; st >= 1; st >>= 1) {
        if (tid < st) {
            double ov = rv[tid + st]; int oi = ri[tid + st];
            if (ov > rv[tid] || (ov == rv[tid] && oi < ri[tid])) { rv[tid] = ov; ri[tid] = oi; }
            rt[tid] += rt[tid + st]; rs[tid] += rs[tid + st];
        }
        __syncthreads();
    }
    if (tid == 0) { sTot = rt[0]; sC = rs[0] / rt[0]; }
    __syncthreads();
    double c = sC, totv = sTot;
    double s2 = 0.0;
    for (int i = tid; i < nf; i += 256) {
        double f = (double)(i + 1) / (double)nf;
        double d = f - c;
        s2 += base[i] * d * d;
    }
    rt[tid] = s2;
    __syncthreads();
    for (int st = 128; st >= 1; st >>= 1) {
        if (tid < st) rt[tid] += rt[tid + st];
        __syncthreads();
    }
    if (tid == 0) {
        double dp, bw;
        if (n < 4) { dp = (double)(n > 0 ? n : 1); bw = 0.0; }
        else if (!(totv > 0.0)) { dp = (double)n; bw = 0.0; }
        else { int kk = ri[0] + 1; dp = (double)n / (double)kk; bw = sqrt(rt[0] / totv); }
        double raw = 1.0 * dp / (1.0 + 1.0 * bw);
        double rr = rint(raw / 2.0);          // Python round(): half-to-even
        long pl = 2L * (long)rr;
        if (pl < 8) pl = 8;
        if (pl > 64) pl = 64;
        int nfull = n / (int)pl;
        int ntok = nfull + ((nfull * (int)pl < n) ? 1 : 0);
        segPL[b * 512 + j] = (int)pl; segDP[b * 512 + j] = dp;
        segBW[b * 512 + j] = bw; segNT[b * 512 + j] = ntok;
    }
}

// ---------------- token prefix offsets per batch
__global__ void k_tokpref(const int* __restrict__ nsegA, const int* __restrict__ segNT,
                          int* __restrict__ tokoff, int* __restrict__ ntokA) {
    int b = threadIdx.x;
    if (b >= Bn) return;
    int ns = nsegA[b]; int off = 0;
    for (int j = 0; j < ns; j++) { tokoff[b * 513 + j] = off; off += segNT[b * 512 + j]; }
    tokoff[b * 513 + ns] = off;
    ntokA[b] = off;
}

// ---------------- fill all outputs: one block per (batch, token)
__global__ __launch_bounds__(256) void k_fill(const float* __restrict__ x,
                                              const int* __restrict__ segS, const int* __restrict__ segE,
                                              const int* __restrict__ segPL, const double* __restrict__ segDP,
                                              const double* __restrict__ segBW, const int* __restrict__ nsegA,
                                              const int* __restrict__ tokoff, const int* __restrict__ ntokA,
                                              float* __restrict__ out, int MT) {
    int b = blockIdx.y, tok = blockIdx.x;
    int nt = ntokA[b];
    if (tok >= nt) return;
    int ns = nsegA[b];
    const int* toff = tokoff + b * 513;
    int lo = 0, hi = ns - 1;
    while (lo < hi) { int mid = (lo + hi + 1) >> 1; if (toff[mid] <= tok) lo = mid; else hi = mid - 1; }
    int j = lo;
    int s = segS[b * 512 + j], e = segE[b * 512 + j], pl = segPL[b * 512 + j];
    int idx = tok - toff[j];
    int nfull = (e - s) / pl;
    int st, en;
    if (idx < nfull) { st = s + idx * pl; en = st + pl; }
    else { st = s + nfull * pl; en = e; }
    int ilen = en - st;
    float scale = (float)ilen / 16.0f;
    int tid = threadIdx.x;
    size_t pbase = ((size_t)(b * MT + tok)) * (Cn * 16);
    const float* xb = x + (size_t)b * Cn * Ln;
    #pragma unroll
    for (int r = 0; r < 2; r++) {
        int eidx = tid + r * 256;
        int c = eidx >> 4, jo = eidx & 15;
        float coords = ((float)jo + 0.5f) * scale - 0.5f;
        if (coords < 0.0f) coords = 0.0f;
        float mx = (float)(ilen - 1);
        if (coords > mx) coords = mx;
        int l2 = (int)floorf(coords);
        int h2 = l2 + 1;
        if (h2 > ilen - 1) h2 = ilen - 1;
        float w = coords - (float)l2;
        const float* xc = xb + (size_t)c * Ln + st;
        out[pbase + eidx] = xc[l2] * (1.0f - w) + xc[h2] * w;
    }
    if (tid == 0) {
        size_t BT = (size_t)Bn * MT;
        size_t o_mask = BT * 512;
        size_t pos = (size_t)b * MT + tok;
        out[o_mask + pos] = 1.0f;                                  // mask
        out[o_mask + BT + pos] = (float)st;                        // start
        out[o_mask + 2 * BT + pos] = (float)en;                    // end
        out[o_mask + 3 * BT + pos] = (((float)st + (float)en) - 1.0f) * 0.5f / 16383.0f;  // center
        out[o_mask + 4 * BT + pos] = (float)(en - st) / 16384.0f;  // span
        double dp = segDP[b * 512 + j], bwv = segBW[b * 512 + j];
        size_t o_rg = o_mask + 5 * BT;
        out[o_rg + pos * 3 + 0] = (float)(dp / 16384.0);
        out[o_rg + pos * 3 + 1] = (float)bwv;
        out[o_rg + pos * 3 + 2] = (float)((double)(e - s) / 16384.0);
        if (tok == 0) out[o_mask + 8 * BT + b] = (float)nt;        // n_tok
    }
}

extern "C" void kernel_launch(void* const* d_in, const int* in_sizes, int n_in,
                              void* d_out, int out_size, void* d_ws, size_t ws_size,
                              hipStream_t stream) {
    (void)in_sizes; (void)n_in;
    const float* x = (const float*)d_in[0];
    float* out = (float*)d_out;
    char* ws = (char*)d_ws;
    size_t o = 0;
    auto alloc = [&](size_t bytes) -> char* {
        char* r = ws + o;
        o = (o + bytes + 511) & ~(size_t)511;
        return r;
    };
    float* sig = (float*)alloc((size_t)Bn * Ln * 4);
    float* fm = (float*)alloc((size_t)Bn * NF * 4);
    double* feats = (double*)alloc((size_t)Bn * NF * NB * 8);
    double* cs = (double*)alloc((size_t)Bn * 512 * NB * 8);
    double* cs2 = (double*)alloc((size_t)Bn * 512 * NB * 8);
    int* prevG = (int*)alloc((size_t)Bn * 512 * 4);
    int* nsegA = (int*)alloc((size_t)Bn * 4);
    int* segS = (int*)alloc((size_t)Bn * 512 * 4);
    int* segE = (int*)alloc((size_t)Bn * 512 * 4);
    int* segPL = (int*)alloc((size_t)Bn * 512 * 4);
    int* segNT = (int*)alloc((size_t)Bn * 512 * 4);
    double* segDP = (double*)alloc((size_t)Bn * 512 * 8);
    double* segBW = (double*)alloc((size_t)Bn * 512 * 8);
    double* segMean = (double*)alloc((size_t)Bn * 512 * 8);
    int* binoff = (int*)alloc((size_t)Bn * 513 * 4);
    int* tokoff = (int*)alloc((size_t)Bn * 513 * 4);
    int* ntokA = (int*)alloc((size_t)Bn * 4);
    double* spec = (double*)alloc((size_t)Bn * TB * 8);
    size_t costBytes = (size_t)Bn * 512 * 512 * 8;   // 67 MB
    double* costM = (double*)alloc(costBytes);
    bool haveCost = (o <= ws_size);

    int MT = (out_size / Bn - 1) / 520;   // out_size = Bn*(MT*520 + 1)

    hipMemsetAsync(d_out, 0, (size_t)out_size * 4, stream);
    k_sig<<<(Bn * Ln + 255) / 256, 256, 0, stream>>>(x, sig);
    k_fmean<<<(Bn * NF + 255) / 256, 256, 0, stream>>>(sig, fm);
    k_feats<<<Bn * NF, 64, 0, stream>>>(sig, fm, feats);
    k_cumsum<<<(Bn * NB + 255) / 256, 256, 0, stream>>>(feats, cs, cs2);
    if (haveCost) {
        k_cost<<<dim3(NF, Bn), 256, 0, stream>>>(cs, cs2, costM);
        k_pelt<<<Bn, 64, 0, stream>>>(costM, prevG);
    } else {
        k_pelt_slow<<<Bn, 64, 0, stream>>>(cs, cs2, prevG);
    }
    k_bounds<<<Bn, 64, 0, stream>>>(prevG, segS, segE, nsegA, binoff);
    k_segmean<<<dim3(MAXSEG, Bn), 256, 0, stream>>>(sig, segS, segE, nsegA, segMean);
    k_spec<<<dim3(TB / 4, Bn), 256, 0, stream>>>(sig, segMean, segS, segE, nsegA, binoff, spec);
    k_stats<<<dim3(MAXSEG, Bn), 256, 0, stream>>>(spec, segS, segE, nsegA, binoff,
                                                  segPL, segDP, segBW, segNT);
    k_tokpref<<<1, 32, 0, stream>>>(nsegA, segNT, tokoff, ntokA);
    if (MT > 0)
        k_fill<<<dim3(MT, Bn), 256, 0, stream>>>(x, segS, segE, segPL, segDP, segBW,
                                                 nsegA, tokoff, ntokA, out, MT);
}